// Round 1
// baseline (2999.472 us; speedup 1.0000x reference)
//
#include <hip/hip_runtime.h>
#include <cstdint>
#include <cstddef>

#define D_MODEL   1024
#define D_STATE   64
#define D_CONV    4
#define HEADDIM   128
#define NHEADS    16
#define D_INNER   2048
#define CONV_DIM  2176          // D_INNER + 2*D_STATE
#define D_IN_PROJ 4240          // 2*D_INNER + 2*D_STATE + NHEADS
#define BATCH     2
#define SEQLEN    2048
#define NROWS     (BATCH*SEQLEN)   // 4096

// ---------------------------------------------------------------------------
// GEMM (NT): C[M,N] = A[M,K] @ B[N,K]^T   (fp32, 64x64 tile, 4x4 per thread)
// M must be a multiple of 64; N is bounds-checked.
// ---------------------------------------------------------------------------
__global__ __launch_bounds__(256) void gemm_nt(const float* __restrict__ A,
                                               const float* __restrict__ B,
                                               float* __restrict__ C,
                                               int M, int N, int K)
{
    __shared__ float As[16][64];
    __shared__ float Bs[16][64];
    const int tid  = threadIdx.x;
    const int tx   = tid & 15, ty = tid >> 4;
    const int row0 = blockIdx.y * 64, col0 = blockIdx.x * 64;
    const int lr   = tid >> 2;         // 0..63
    const int lc   = (tid & 3) << 2;   // 0,4,8,12

    float acc[4][4] = {};
    const int brow = col0 + lr;
    const float* Aptr = A + (size_t)(row0 + lr) * K + lc;
    const float* Bptr = (brow < N) ? (B + (size_t)brow * K + lc) : nullptr;

    for (int k0 = 0; k0 < K; k0 += 16) {
        float4 a4 = *(const float4*)(Aptr + k0);
        float4 b4 = make_float4(0.f, 0.f, 0.f, 0.f);
        if (Bptr) b4 = *(const float4*)(Bptr + k0);
        __syncthreads();
        As[lc+0][lr]=a4.x; As[lc+1][lr]=a4.y; As[lc+2][lr]=a4.z; As[lc+3][lr]=a4.w;
        Bs[lc+0][lr]=b4.x; Bs[lc+1][lr]=b4.y; Bs[lc+2][lr]=b4.z; Bs[lc+3][lr]=b4.w;
        __syncthreads();
        #pragma unroll
        for (int k = 0; k < 16; ++k) {
            float4 av = *(const float4*)&As[k][ty << 2];
            float4 bv = *(const float4*)&Bs[k][tx << 2];
            float a[4] = {av.x, av.y, av.z, av.w};
            float b[4] = {bv.x, bv.y, bv.z, bv.w};
            #pragma unroll
            for (int i = 0; i < 4; ++i)
                #pragma unroll
                for (int j = 0; j < 4; ++j)
                    acc[i][j] = fmaf(a[i], b[j], acc[i][j]);
        }
    }
    #pragma unroll
    for (int i = 0; i < 4; ++i) {
        int r = row0 + (ty << 2) + i;
        #pragma unroll
        for (int j = 0; j < 4; ++j) {
            int c = col0 + (tx << 2) + j;
            if (c < N) C[(size_t)r * N + c] = acc[i][j];
        }
    }
}

// ---------------------------------------------------------------------------
// Depthwise causal conv(4) + bias + SiLU over xBC slice of zxbcdt
// ---------------------------------------------------------------------------
__global__ __launch_bounds__(256) void conv_silu(const float* __restrict__ zxbcdt,
                                                 const float* __restrict__ conv_w,
                                                 const float* __restrict__ conv_b,
                                                 float* __restrict__ xconv)
{
    int idx = blockIdx.x * 256 + threadIdx.x;
    if (idx >= NROWS * CONV_DIM) return;
    int c   = idx % CONV_DIM;
    int row = idx / CONV_DIM;      // b*SEQLEN + l
    int l   = row % SEQLEN;
    int b   = row / SEQLEN;
    float w0 = conv_w[c*4+0], w1 = conv_w[c*4+1], w2 = conv_w[c*4+2], w3 = conv_w[c*4+3];
    const float* src = zxbcdt + (size_t)(b * SEQLEN) * D_IN_PROJ + D_INNER + c;
    float acc = conv_b[c];
    if (l >= 3) {
        acc += src[(size_t)(l-3)*D_IN_PROJ]*w0 + src[(size_t)(l-2)*D_IN_PROJ]*w1
             + src[(size_t)(l-1)*D_IN_PROJ]*w2 + src[(size_t)l*D_IN_PROJ]*w3;
    } else {
        if (l >= 2) acc += src[(size_t)(l-2)*D_IN_PROJ]*w1;
        if (l >= 1) acc += src[(size_t)(l-1)*D_IN_PROJ]*w2;
        acc += src[(size_t)l*D_IN_PROJ]*w3;
    }
    xconv[idx] = acc / (1.f + expf(-acc));   // SiLU
}

// ---------------------------------------------------------------------------
// dt = softplus(zxbcdt[..., 4224:4240] + dt_bias)
// ---------------------------------------------------------------------------
__global__ __launch_bounds__(256) void dt_softplus(const float* __restrict__ zxbcdt,
                                                   const float* __restrict__ dt_bias,
                                                   float* __restrict__ dtw)
{
    int idx = blockIdx.x * 256 + threadIdx.x;
    if (idx >= NROWS * NHEADS) return;
    int h   = idx & (NHEADS - 1);
    int row = idx / NHEADS;
    float v = zxbcdt[(size_t)row * D_IN_PROJ + D_INNER + CONV_DIM + h] + dt_bias[h];
    dtw[idx] = (v > 20.f) ? v : log1pf(expf(v));
}

// ---------------------------------------------------------------------------
// Selective scan: one block per (b,h); lane = p (128 threads), 64 n-states
// in registers per lane. B_t/C_t staged in LDS (broadcast float4 reads).
// ---------------------------------------------------------------------------
__global__ __launch_bounds__(128) void scan_kernel(const float* __restrict__ xconv,
                                                   const float* __restrict__ dtw,
                                                   const float* __restrict__ A_log,
                                                   const float* __restrict__ D_param,
                                                   float* __restrict__ y)
{
    const int bh = blockIdx.x;
    const int b  = bh >> 4;
    const int h  = bh & 15;
    const int p  = threadIdx.x;            // 0..127

    const float A  = -expf(A_log[h]);
    const float Dp = D_param[h];

    __shared__ float sB[D_STATE];
    __shared__ float sC[D_STATE];

    float st[D_STATE];
    #pragma unroll
    for (int n = 0; n < D_STATE; ++n) st[n] = 0.f;

    const float* xc_base = xconv + (size_t)b * SEQLEN * CONV_DIM;
    const float* dt_base = dtw   + (size_t)b * SEQLEN * NHEADS + h;
    float*       y_base  = y     + (size_t)b * SEQLEN * D_INNER + h * HEADDIM + p;

    for (int t = 0; t < SEQLEN; ++t) {
        const float* row = xc_base + (size_t)t * CONV_DIM;
        float dt_t = dt_base[(size_t)t * NHEADS];
        float x_p  = row[h * HEADDIM + p];
        __syncthreads();                 // protect previous-iter LDS reads
        if (p < D_STATE) sB[p] = row[D_INNER + p];
        else             sC[p - D_STATE] = row[D_INNER + D_STATE + (p - D_STATE)];
        __syncthreads();

        const float dA = expf(dt_t * A);
        const float su = dt_t * x_p;
        float accv = 0.f;
        #pragma unroll
        for (int n4 = 0; n4 < D_STATE/4; ++n4) {
            float4 b4 = *(const float4*)&sB[n4*4];
            float4 c4 = *(const float4*)&sC[n4*4];
            st[4*n4+0] = st[4*n4+0]*dA + su*b4.x; accv += st[4*n4+0]*c4.x;
            st[4*n4+1] = st[4*n4+1]*dA + su*b4.y; accv += st[4*n4+1]*c4.y;
            st[4*n4+2] = st[4*n4+2]*dA + su*b4.z; accv += st[4*n4+2]*c4.z;
            st[4*n4+3] = st[4*n4+3]*dA + su*b4.w; accv += st[4*n4+3]*c4.w;
        }
        y_base[(size_t)t * D_INNER] = accv + Dp * x_p;
    }
}

// ---------------------------------------------------------------------------
// yg = y * silu(z); RMSNorm over D_INNER; yn = yg * rsqrt(mean(yg^2)+eps) * w
// One block per (b,l) row.
// ---------------------------------------------------------------------------
__global__ __launch_bounds__(256) void gate_rmsnorm(const float* __restrict__ zxbcdt,
                                                    const float* __restrict__ y,
                                                    const float* __restrict__ norm_w,
                                                    float* __restrict__ yn)
{
    const int row = blockIdx.x;          // b*SEQLEN + l
    const int tid = threadIdx.x;
    const float* z  = zxbcdt + (size_t)row * D_IN_PROJ;
    const float* yr = y      + (size_t)row * D_INNER;
    float*       o  = yn     + (size_t)row * D_INNER;

    float vals[8];
    float ss = 0.f;
    #pragma unroll
    for (int i = 0; i < 8; ++i) {
        int c = tid + i * 256;
        float zv = z[c];
        float g  = yr[c] * (zv / (1.f + expf(-zv)));
        vals[i] = g;
        ss += g * g;
    }
    #pragma unroll
    for (int off = 32; off > 0; off >>= 1) ss += __shfl_down(ss, off);
    __shared__ float red[4];
    __shared__ float sscale;
    int wid = tid >> 6, lane = tid & 63;
    if (lane == 0) red[wid] = ss;
    __syncthreads();
    if (tid == 0)
        sscale = rsqrtf((red[0]+red[1]+red[2]+red[3]) / (float)D_INNER + 1e-5f);
    __syncthreads();
    float rms = sscale;
    #pragma unroll
    for (int i = 0; i < 8; ++i) {
        int c = tid + i * 256;
        o[c] = vals[i] * rms * norm_w[c];
    }
}

// ---------------------------------------------------------------------------
extern "C" void kernel_launch(void* const* d_in, const int* in_sizes, int n_in,
                              void* d_out, int out_size, void* d_ws, size_t ws_size,
                              hipStream_t stream)
{
    const float* u          = (const float*)d_in[0];
    const float* in_proj_w  = (const float*)d_in[1];
    const float* conv_w     = (const float*)d_in[2];
    const float* conv_b     = (const float*)d_in[3];
    const float* dt_bias    = (const float*)d_in[4];
    const float* A_log      = (const float*)d_in[5];
    const float* D_param    = (const float*)d_in[6];
    const float* norm_w     = (const float*)d_in[7];
    const float* out_proj_w = (const float*)d_in[8];
    float* out = (float*)d_out;

    float* ws     = (float*)d_ws;
    float* zxbcdt = ws;                                        // 4096*4240
    float* xconv  = zxbcdt + (size_t)NROWS * D_IN_PROJ;        // 4096*2176
    float* dtw    = xconv  + (size_t)NROWS * CONV_DIM;         // 4096*16
    float* yb     = dtw    + (size_t)NROWS * NHEADS;           // 4096*2048
    float* yn     = xconv;   // xconv dead after scan; reuse for normed output

    // 1) in_proj GEMM: zxbcdt[4096,4240] = u[4096,1024] @ W^T
    dim3 g1((D_IN_PROJ + 63) / 64, NROWS / 64);
    gemm_nt<<<g1, 256, 0, stream>>>(u, in_proj_w, zxbcdt, NROWS, D_IN_PROJ, D_MODEL);

    // 2) conv + SiLU
    int nconv = NROWS * CONV_DIM;
    conv_silu<<<(nconv + 255) / 256, 256, 0, stream>>>(zxbcdt, conv_w, conv_b, xconv);

    // 3) dt softplus
    dt_softplus<<<(NROWS * NHEADS + 255) / 256, 256, 0, stream>>>(zxbcdt, dt_bias, dtw);

    // 4) selective scan
    scan_kernel<<<BATCH * NHEADS, 128, 0, stream>>>(xconv, dtw, A_log, D_param, yb);

    // 5) gate + RMSNorm
    gate_rmsnorm<<<NROWS, 256, 0, stream>>>(zxbcdt, yb, norm_w, yn);

    // 6) out_proj GEMM: out[4096,1024] = yn[4096,2048] @ Wo^T
    dim3 g6(D_MODEL / 64, NROWS / 64);
    gemm_nt<<<g6, 256, 0, stream>>>(yn, out_proj_w, out, NROWS, D_MODEL, D_INNER);
}

// Round 2
// 1163.257 us; speedup vs baseline: 2.5785x; 2.5785x over previous
//
#include <hip/hip_runtime.h>
#include <cstdint>
#include <cstddef>

#define D_MODEL   1024
#define D_STATE   64
#define D_CONV    4
#define HEADDIM   128
#define NHEADS    16
#define D_INNER   2048
#define CONV_DIM  2176          // D_INNER + 2*D_STATE
#define D_IN_PROJ 4240          // 2*D_INNER + 2*D_STATE + NHEADS
#define BATCH     2
#define SEQLEN    2048
#define NROWS     (BATCH*SEQLEN)   // 4096
#define CHUNK     64
#define NCHUNK    (SEQLEN/CHUNK)   // 32

// ---------------------------------------------------------------------------
// GEMM (NT): C[M,N] = A[M,K] @ B[N,K]^T  (fp32, 64x64 tile, 4x4 per thread)
// Output routed to up to 3 buffers by column: c<n1 -> C0, c<n2 -> C1, else C2.
// ---------------------------------------------------------------------------
__global__ __launch_bounds__(256) void gemm_nt_split(
    const float* __restrict__ A, const float* __restrict__ B,
    int M, int N, int K,
    float* __restrict__ C0, int n1, int ld0,
    float* __restrict__ C1, int n2, int ld1,
    float* __restrict__ C2, int ld2)
{
    __shared__ float As[16][64];
    __shared__ float Bs[16][64];
    const int tid  = threadIdx.x;
    const int tx   = tid & 15, ty = tid >> 4;
    const int row0 = blockIdx.y * 64, col0 = blockIdx.x * 64;
    const int lr   = tid >> 2;         // 0..63
    const int lc   = (tid & 3) << 2;   // 0,4,8,12

    float acc[4][4] = {};
    const int brow = col0 + lr;
    const float* Aptr = A + (size_t)(row0 + lr) * K + lc;
    const float* Bptr = (brow < N) ? (B + (size_t)brow * K + lc) : nullptr;

    for (int k0 = 0; k0 < K; k0 += 16) {
        float4 a4 = *(const float4*)(Aptr + k0);
        float4 b4 = make_float4(0.f, 0.f, 0.f, 0.f);
        if (Bptr) b4 = *(const float4*)(Bptr + k0);
        __syncthreads();
        As[lc+0][lr]=a4.x; As[lc+1][lr]=a4.y; As[lc+2][lr]=a4.z; As[lc+3][lr]=a4.w;
        Bs[lc+0][lr]=b4.x; Bs[lc+1][lr]=b4.y; Bs[lc+2][lr]=b4.z; Bs[lc+3][lr]=b4.w;
        __syncthreads();
        #pragma unroll
        for (int k = 0; k < 16; ++k) {
            float4 av = *(const float4*)&As[k][ty << 2];
            float4 bv = *(const float4*)&Bs[k][tx << 2];
            float a[4] = {av.x, av.y, av.z, av.w};
            float b[4] = {bv.x, bv.y, bv.z, bv.w};
            #pragma unroll
            for (int i = 0; i < 4; ++i)
                #pragma unroll
                for (int j = 0; j < 4; ++j)
                    acc[i][j] = fmaf(a[i], b[j], acc[i][j]);
        }
    }
    #pragma unroll
    for (int i = 0; i < 4; ++i) {
        int r = row0 + (ty << 2) + i;
        #pragma unroll
        for (int j = 0; j < 4; ++j) {
            int c = col0 + (tx << 2) + j;
            if (c >= N) continue;
            if (c < n1)      C0[(size_t)r * ld0 + c]        = acc[i][j];
            else if (c < n2) C1[(size_t)r * ld1 + (c - n1)] = acc[i][j];
            else             C2[(size_t)r * ld2 + (c - n2)] = acc[i][j];
        }
    }
}

// ---------------------------------------------------------------------------
// Depthwise causal conv(4) + bias + SiLU. xBC layout: [NROWS][CONV_DIM].
// ---------------------------------------------------------------------------
__global__ __launch_bounds__(256) void conv_silu(const float* __restrict__ xBC,
                                                 const float* __restrict__ conv_w,
                                                 const float* __restrict__ conv_b,
                                                 float* __restrict__ xconv)
{
    int idx = blockIdx.x * 256 + threadIdx.x;
    if (idx >= NROWS * CONV_DIM) return;
    int c   = idx % CONV_DIM;
    int row = idx / CONV_DIM;      // b*SEQLEN + l
    int l   = row % SEQLEN;
    int b   = row / SEQLEN;
    float w0 = conv_w[c*4+0], w1 = conv_w[c*4+1], w2 = conv_w[c*4+2], w3 = conv_w[c*4+3];
    const float* src = xBC + (size_t)(b * SEQLEN) * CONV_DIM + c;
    float acc = conv_b[c];
    if (l >= 3) {
        acc += src[(size_t)(l-3)*CONV_DIM]*w0 + src[(size_t)(l-2)*CONV_DIM]*w1
             + src[(size_t)(l-1)*CONV_DIM]*w2 + src[(size_t)l*CONV_DIM]*w3;
    } else {
        if (l >= 2) acc += src[(size_t)(l-2)*CONV_DIM]*w1;
        if (l >= 1) acc += src[(size_t)(l-1)*CONV_DIM]*w2;
        acc += src[(size_t)l*CONV_DIM]*w3;
    }
    xconv[idx] = acc / (1.f + expf(-acc));   // SiLU
}

// ---------------------------------------------------------------------------
// dt = softplus(dtraw + dt_bias)
// ---------------------------------------------------------------------------
__global__ __launch_bounds__(256) void dt_softplus(const float* __restrict__ dtraw,
                                                   const float* __restrict__ dt_bias,
                                                   float* __restrict__ dtw)
{
    int idx = blockIdx.x * 256 + threadIdx.x;
    if (idx >= NROWS * NHEADS) return;
    int h = idx & (NHEADS - 1);
    float v = dtraw[idx] + dt_bias[h];
    dtw[idx] = (v > 20.f) ? v : log1pf(expf(v));
}

// ---------------------------------------------------------------------------
// Phase A: per-(b,h,chunk) local chunk state
//   S_chunk[n][p] = sum_s exp(T - L_s) * dt_s * x_s[p] * B_s[n]
// ---------------------------------------------------------------------------
__global__ __launch_bounds__(256) void chunk_state(
    const float* __restrict__ xconv, const float* __restrict__ dtw,
    const float* __restrict__ A_log, float* __restrict__ Sbuf,
    float* __restrict__ Tbuf)
{
    const int blk = blockIdx.x;
    const int k  = blk & (NCHUNK-1);
    const int bh = blk >> 5;               // NCHUNK = 32
    const int b  = bh >> 4, h = bh & 15;
    const int tid = threadIdx.x;
    const float A = -expf(A_log[h]);

    __shared__ float sdt[CHUNK], sL[CHUNK], sW[CHUNK];
    __shared__ float sB[CHUNK][D_STATE];

    const int t0 = k * CHUNK;
    const float* xc = xconv + (size_t)(b*SEQLEN + t0) * CONV_DIM;

    if (tid < CHUNK)
        sdt[tid] = dtw[(size_t)(b*SEQLEN + t0 + tid)*NHEADS + h];
    for (int i = tid; i < CHUNK*D_STATE; i += 256) {
        int s = i >> 6, n = i & 63;
        sB[s][n] = xc[(size_t)s*CONV_DIM + D_INNER + n];
    }
    __syncthreads();
    if (tid < CHUNK) {
        float a = 0.f;
        for (int r = 0; r <= tid; ++r) a += sdt[r] * A;
        sL[tid] = a;
    }
    __syncthreads();
    const float T = sL[CHUNK-1];
    if (tid < CHUNK) sW[tid] = __expf(T - sL[tid]) * sdt[tid];
    __syncthreads();

    const int p = tid & 127, nh = tid >> 7;   // n-range nh*32..+32
    float acc[32];
    #pragma unroll
    for (int i = 0; i < 32; ++i) acc[i] = 0.f;
    for (int s = 0; s < CHUNK; ++s) {
        float xs = xc[(size_t)s*CONV_DIM + h*HEADDIM + p];
        float wx = sW[s] * xs;
        #pragma unroll
        for (int i4 = 0; i4 < 8; ++i4) {
            float4 b4 = *(const float4*)&sB[s][nh*32 + i4*4];
            acc[i4*4+0] += wx*b4.x; acc[i4*4+1] += wx*b4.y;
            acc[i4*4+2] += wx*b4.z; acc[i4*4+3] += wx*b4.w;
        }
    }
    float* So = Sbuf + ((size_t)bh*NCHUNK + k)*(D_STATE*HEADDIM);
    #pragma unroll
    for (int i = 0; i < 32; ++i)
        So[(size_t)(nh*32+i)*HEADDIM + p] = acc[i];
    if (tid == 0) Tbuf[bh*NCHUNK + k] = T;
}

// ---------------------------------------------------------------------------
// Inter-chunk sequential pass: replaces S_chunk slots with S_init (state at
// chunk start).  run_{k+1} = run_k * exp(T_k) + S_chunk_k
// ---------------------------------------------------------------------------
__global__ __launch_bounds__(128) void chunk_seq(float* __restrict__ Sbuf,
                                                 const float* __restrict__ Tbuf)
{
    const int bh = blockIdx.x;
    const int p  = threadIdx.x;
    float* Sb = Sbuf + (size_t)bh*NCHUNK*(D_STATE*HEADDIM);
    const float* Tb = Tbuf + bh*NCHUNK;
    float run[D_STATE];
    #pragma unroll
    for (int n = 0; n < D_STATE; ++n) run[n] = 0.f;
    for (int k = 0; k < NCHUNK; ++k) {
        float eT = __expf(Tb[k]);
        float* Sk = Sb + (size_t)k*(D_STATE*HEADDIM);
        #pragma unroll
        for (int n = 0; n < D_STATE; ++n) {
            float tmp = Sk[(size_t)n*HEADDIM + p];
            Sk[(size_t)n*HEADDIM + p] = run[n];
            run[n] = run[n]*eT + tmp;
        }
    }
}

// ---------------------------------------------------------------------------
// Phase B: per-(b,h,chunk) outputs.
//   y[t,p] = sum_{s<=t} exp(L_t-L_s) dt_s (C_t.B_s) x_s[p]
//          + exp(L_t) * sum_n C_t[n] * S_init[n][p] + D*x_t[p]
// M stored transposed in LDS: sMt[s][t]; ext rows sMt[64+n][t] = exp(L_t)C_t[n]
// ---------------------------------------------------------------------------
__global__ __launch_bounds__(256) void chunk_output(
    const float* __restrict__ xconv, const float* __restrict__ dtw,
    const float* __restrict__ A_log, const float* __restrict__ D_param,
    const float* __restrict__ Sbuf, float* __restrict__ y)
{
    const int blk = blockIdx.x;
    const int k  = blk & (NCHUNK-1);
    const int bh = blk >> 5;
    const int b  = bh >> 4, h = bh & 15;
    const int tid = threadIdx.x;
    const float A  = -expf(A_log[h]);
    const float Dp = D_param[h];

    __shared__ float sdt[CHUNK], sL[CHUNK], sedA[CHUNK], seL[CHUNK];
    __shared__ float sB[CHUNK][D_STATE];
    __shared__ float sMt[CHUNK + D_STATE][CHUNK];   // row s (or 64+n), col t

    const int t0 = k * CHUNK;
    const float* xc = xconv + (size_t)(b*SEQLEN + t0) * CONV_DIM;

    if (tid < CHUNK)
        sdt[tid] = dtw[(size_t)(b*SEQLEN + t0 + tid)*NHEADS + h];
    for (int i = tid; i < CHUNK*D_STATE; i += 256) {
        int s = i >> 6, n = i & 63;
        sB[s][n] = xc[(size_t)s*CONV_DIM + D_INNER + n];
    }
    __syncthreads();
    if (tid < CHUNK) {
        float a = 0.f;
        for (int r = 0; r <= tid; ++r) a += sdt[r] * A;
        sL[tid]   = a;
        sedA[tid] = __expf(sdt[tid] * A);
        seL[tid]  = __expf(a);
    }
    __syncthreads();

    // ---- stage 1: M (transposed) + ext rows ----
    {
        const int t    = tid & 63;
        const int sh   = tid >> 6;           // 0..3
        const int sbeg = sh * 16;
        float4 c4[16];
        const float4* Crow = (const float4*)(xc + (size_t)t*CONV_DIM + D_INNER + D_STATE);
        #pragma unroll
        for (int i = 0; i < 16; ++i) c4[i] = Crow[i];

        const int shi = (t < sbeg + 15) ? t : (sbeg + 15);
        if (shi >= sbeg) {
            float e = __expf(sL[t] - sL[shi]);   // running exp(L_t - L_s)
            for (int s = shi; s >= sbeg; --s) {
                float dot = 0.f;
                #pragma unroll
                for (int i = 0; i < 16; ++i) {
                    float4 b4 = *(const float4*)&sB[s][i*4];
                    dot += c4[i].x*b4.x + c4[i].y*b4.y
                         + c4[i].z*b4.z + c4[i].w*b4.w;
                }
                sMt[s][t] = e * sdt[s] * dot;
                e *= sedA[s];
            }
        }
        for (int s = (shi >= sbeg ? shi+1 : sbeg); s < sbeg + 16; ++s)
            sMt[s][t] = 0.f;
        // ext rows: n in [sh*16, sh*16+16)
        const float* CrowS = xc + (size_t)t*CONV_DIM + D_INNER + D_STATE;
        const float el = seL[t];
        #pragma unroll
        for (int j = 0; j < 16; ++j) {
            int n = sbeg + j;
            sMt[CHUNK + n][t] = el * CrowS[n];
        }
    }
    __syncthreads();

    // ---- stage 2: Y = M_ext @ [X ; S_init] ----
    {
        const int p  = tid & 127;
        const int th = tid >> 7;             // t-range th*32..+32
        const float* Sinit = Sbuf + ((size_t)bh*NCHUNK + k)*(D_STATE*HEADDIM);
        float acc[32];
        #pragma unroll
        for (int i = 0; i < 32; ++i) acc[i] = 0.f;

        const int smax = th ? CHUNK : 32;    // causal trim
        for (int s = 0; s < smax; ++s) {
            float xs = xc[(size_t)s*CONV_DIM + h*HEADDIM + p];
            #pragma unroll
            for (int i4 = 0; i4 < 8; ++i4) {
                float4 m4 = *(const float4*)&sMt[s][th*32 + i4*4];
                acc[i4*4+0] += m4.x*xs; acc[i4*4+1] += m4.y*xs;
                acc[i4*4+2] += m4.z*xs; acc[i4*4+3] += m4.w*xs;
            }
        }
        for (int n = 0; n < D_STATE; ++n) {
            float xs = Sinit[(size_t)n*HEADDIM + p];
            #pragma unroll
            for (int i4 = 0; i4 < 8; ++i4) {
                float4 m4 = *(const float4*)&sMt[CHUNK + n][th*32 + i4*4];
                acc[i4*4+0] += m4.x*xs; acc[i4*4+1] += m4.y*xs;
                acc[i4*4+2] += m4.z*xs; acc[i4*4+3] += m4.w*xs;
            }
        }
        float* yrow = y + ((size_t)(b*SEQLEN + t0 + th*32))*D_INNER + h*HEADDIM + p;
        #pragma unroll
        for (int i = 0; i < 32; ++i) {
            int t = th*32 + i;
            float xt = xc[(size_t)t*CONV_DIM + h*HEADDIM + p];
            yrow[(size_t)i*D_INNER] = acc[i] + Dp*xt;
        }
    }
}

// ---------------------------------------------------------------------------
// yg = y * silu(z); RMSNorm over D_INNER. One block per (b,l) row.
// ---------------------------------------------------------------------------
__global__ __launch_bounds__(256) void gate_rmsnorm(const float* __restrict__ z,
                                                    const float* __restrict__ y,
                                                    const float* __restrict__ norm_w,
                                                    float* __restrict__ yn)
{
    const int row = blockIdx.x;
    const int tid = threadIdx.x;
    const float* zr = z + (size_t)row * D_INNER;
    const float* yr = y + (size_t)row * D_INNER;
    float*       o  = yn + (size_t)row * D_INNER;

    float vals[8];
    float ss = 0.f;
    #pragma unroll
    for (int i = 0; i < 8; ++i) {
        int c = tid + i * 256;
        float zv = zr[c];
        float g  = yr[c] * (zv / (1.f + expf(-zv)));
        vals[i] = g;
        ss += g * g;
    }
    #pragma unroll
    for (int off = 32; off > 0; off >>= 1) ss += __shfl_down(ss, off);
    __shared__ float red[4];
    __shared__ float sscale;
    int wid = tid >> 6, lane = tid & 63;
    if (lane == 0) red[wid] = ss;
    __syncthreads();
    if (tid == 0)
        sscale = rsqrtf((red[0]+red[1]+red[2]+red[3]) / (float)D_INNER + 1e-5f);
    __syncthreads();
    float rms = sscale;
    #pragma unroll
    for (int i = 0; i < 8; ++i) {
        int c = tid + i * 256;
        o[c] = vals[i] * rms * norm_w[c];
    }
}

// ---------------------------------------------------------------------------
extern "C" void kernel_launch(void* const* d_in, const int* in_sizes, int n_in,
                              void* d_out, int out_size, void* d_ws, size_t ws_size,
                              hipStream_t stream)
{
    const float* u          = (const float*)d_in[0];
    const float* in_proj_w  = (const float*)d_in[1];
    const float* conv_w     = (const float*)d_in[2];
    const float* conv_b     = (const float*)d_in[3];
    const float* dt_bias    = (const float*)d_in[4];
    const float* A_log      = (const float*)d_in[5];
    const float* D_param    = (const float*)d_in[6];
    const float* norm_w     = (const float*)d_in[7];
    const float* out_proj_w = (const float*)d_in[8];
    float* out = (float*)d_out;

    float* ws    = (float*)d_ws;
    float* z     = ws;                                   // 4096*2048
    float* xBC   = z     + (size_t)NROWS * D_INNER;      // 4096*2176
    float* dtraw = xBC   + (size_t)NROWS * CONV_DIM;     // 4096*16
    float* xconv = dtraw + (size_t)NROWS * NHEADS;       // 4096*2176
    float* dtw   = xconv + (size_t)NROWS * CONV_DIM;     // 4096*16
    float* yb    = dtw   + (size_t)NROWS * NHEADS;       // 4096*2048
    float* Tbuf  = yb    + (size_t)NROWS * D_INNER;      // 1024
    float* Sbuf  = xBC;   // xBC dead after conv_silu; needs 8.39M < 8.91M ok
    float* yn    = xconv; // xconv dead after chunk_output

    // 1) in_proj GEMM (split outputs: z | xBC | dtraw)
    dim3 g1((D_IN_PROJ + 63) / 64, NROWS / 64);
    gemm_nt_split<<<g1, 256, 0, stream>>>(u, in_proj_w, NROWS, D_IN_PROJ, D_MODEL,
                                          z, D_INNER, D_INNER,
                                          xBC, D_INNER + CONV_DIM, CONV_DIM,
                                          dtraw, NHEADS);

    // 2) conv + SiLU
    int nconv = NROWS * CONV_DIM;
    conv_silu<<<(nconv + 255) / 256, 256, 0, stream>>>(xBC, conv_w, conv_b, xconv);

    // 3) dt softplus
    dt_softplus<<<(NROWS * NHEADS + 255) / 256, 256, 0, stream>>>(dtraw, dt_bias, dtw);

    // 4) chunked scan
    chunk_state<<<BATCH*NHEADS*NCHUNK, 256, 0, stream>>>(xconv, dtw, A_log, Sbuf, Tbuf);
    chunk_seq<<<BATCH*NHEADS, 128, 0, stream>>>(Sbuf, Tbuf);
    chunk_output<<<BATCH*NHEADS*NCHUNK, 256, 0, stream>>>(xconv, dtw, A_log, D_param,
                                                          Sbuf, yb);

    // 5) gate + RMSNorm
    gate_rmsnorm<<<NROWS, 256, 0, stream>>>(z, yb, norm_w, yn);

    // 6) out_proj GEMM
    dim3 g6(D_MODEL / 64, NROWS / 64);
    gemm_nt_split<<<g6, 256, 0, stream>>>(yn, out_proj_w, NROWS, D_MODEL, D_INNER,
                                          out, D_MODEL, D_MODEL,
                                          out, D_MODEL, D_MODEL,
                                          out, D_MODEL);
}

// Round 3
// 530.390 us; speedup vs baseline: 5.6552x; 2.1932x over previous
//
#include <hip/hip_runtime.h>
#include <cstdint>
#include <cstddef>

#define D_MODEL   1024
#define D_STATE   64
#define D_CONV    4
#define HEADDIM   128
#define NHEADS    16
#define D_INNER   2048
#define CONV_DIM  2176          // D_INNER + 2*D_STATE
#define D_IN_PROJ 4240          // 2*D_INNER + 2*D_STATE + NHEADS
#define NPAD      4352          // D_IN_PROJ padded to multiple of 128
#define BATCH     2
#define SEQLEN    2048
#define NROWS     (BATCH*SEQLEN)   // 4096
#define CHUNK     64
#define NCHUNK    (SEQLEN/CHUNK)   // 32

using u16   = unsigned short;
using s16x8 = __attribute__((ext_vector_type(8))) short;   // 8 bf16 (4 VGPRs)
using f32x4 = __attribute__((ext_vector_type(4))) float;   // MFMA accumulator

// ---------------------------------------------------------------------------
// helpers
// ---------------------------------------------------------------------------
__device__ __forceinline__ u16 f2bf(float f) {
    union { float f; unsigned u; } v; v.f = f;
    unsigned r = v.u + 0x7fffu + ((v.u >> 16) & 1u);   // round-to-nearest-even
    return (u16)(r >> 16);
}

__device__ __forceinline__ void gload16(const u16* g, u16* l) {
    __builtin_amdgcn_global_load_lds(
        (const __attribute__((address_space(1))) unsigned int*)g,
        (__attribute__((address_space(3))) unsigned int*)l, 16, 0, 0);
}

// ---------------------------------------------------------------------------
// f32 -> bf16 converters (vectorized, 8 elems/thread)
// ---------------------------------------------------------------------------
__global__ __launch_bounds__(256) void cvt_bf16_x8(const float* __restrict__ in,
                                                   u16* __restrict__ out, int n8)
{
    int i = blockIdx.x * 256 + threadIdx.x;
    if (i >= n8) return;
    const float4* p = (const float4*)(in + (size_t)i * 8);
    float4 a = p[0], b = p[1];
    u16 o[8] = {f2bf(a.x), f2bf(a.y), f2bf(a.z), f2bf(a.w),
                f2bf(b.x), f2bf(b.y), f2bf(b.z), f2bf(b.w)};
    *(uint4*)(out + (size_t)i * 8) = *(const uint4*)o;
}

// in_proj_w [4240][1024] -> bf16 [4352][1024], zero-padded rows
__global__ __launch_bounds__(256) void cvt_win_pad(const float* __restrict__ w,
                                                   u16* __restrict__ out)
{
    int i = blockIdx.x * 256 + threadIdx.x;     // 8 elems each
    if (i >= NPAD * 128) return;
    int row = i >> 7, seg = i & 127;
    u16 o[8] = {0, 0, 0, 0, 0, 0, 0, 0};
    if (row < D_IN_PROJ) {
        const float4* p = (const float4*)(w + (size_t)row * D_MODEL + seg * 8);
        float4 a = p[0], b = p[1];
        o[0]=f2bf(a.x); o[1]=f2bf(a.y); o[2]=f2bf(a.z); o[3]=f2bf(a.w);
        o[4]=f2bf(b.x); o[5]=f2bf(b.y); o[6]=f2bf(b.z); o[7]=f2bf(b.w);
    }
    *(uint4*)(out + (size_t)i * 8) = *(const uint4*)o;
}

// ---------------------------------------------------------------------------
// bf16 MFMA GEMM (NT): C[M,N] = A[M,K] @ B[N,K]^T, fp32 out.
// 128x128 tile, BK=64, 4 waves (each 64x64 = 4x4 frags of 16x16x32).
// LDS XOR-swizzled (byte ^= (row&7)<<4) via pre-swizzled global source.
// Split store: c<n1 -> C0, c<n2 -> C1, c<n3 -> C2, else discarded.
// ---------------------------------------------------------------------------
__global__ __launch_bounds__(256) void gemm_bf16_mfma(
    const u16* __restrict__ A, const u16* __restrict__ B, int K,
    float* __restrict__ C0, int n1, int ld0,
    float* __restrict__ C1, int n2, int ld1,
    float* __restrict__ C2, int n3, int ld2)
{
    __shared__ u16 sA[128 * 64];
    __shared__ u16 sB[128 * 64];
    const int tid  = threadIdx.x;
    const int wid  = tid >> 6;
    const int lane = tid & 63;
    const int wm   = wid >> 1, wn = wid & 1;
    const int m0   = blockIdx.y * 128, n0 = blockIdx.x * 128;

    // staging: each wave-issue covers 8 rows (64 lanes x 16B, LDS linear).
    // global k-segment pre-swizzled so swizzled ds_reads see linear data.
    const int lrow = lane >> 3;              // row within 8-row stripe
    const int lseg = (lane & 7) ^ lrow;      // XOR-swizzled 16B segment
    const u16* gA = A + (size_t)(m0 + lrow) * K + lseg * 8;
    const u16* gB = B + (size_t)(n0 + lrow) * K + lseg * 8;

    f32x4 acc[4][4];
    #pragma unroll
    for (int i = 0; i < 4; ++i)
        #pragma unroll
        for (int j = 0; j < 4; ++j)
            acc[i][j] = (f32x4){0.f, 0.f, 0.f, 0.f};

    const int fr = lane & 15, fq = lane >> 4;

    for (int k0 = 0; k0 < K; k0 += 64) {
        #pragma unroll
        for (int i = 0; i < 4; ++i) {
            const int r0 = (i * 4 + wid) * 8;
            gload16(gA + (size_t)r0 * K + k0, sA + r0 * 64);
            gload16(gB + (size_t)r0 * K + k0, sB + r0 * 64);
        }
        __syncthreads();   // compiler drains vmcnt(0) before s_barrier

        s16x8 af[4][2], bfr[4][2];
        #pragma unroll
        for (int mi = 0; mi < 4; ++mi) {
            const int row = wm * 64 + mi * 16 + fr;
            #pragma unroll
            for (int ks = 0; ks < 2; ++ks) {
                const int bo = row * 128 + ((ks * 64 + fq * 16) ^ ((row & 7) << 4));
                af[mi][ks] = *(const s16x8*)((const char*)sA + bo);
            }
        }
        #pragma unroll
        for (int ni = 0; ni < 4; ++ni) {
            const int row = wn * 64 + ni * 16 + fr;
            #pragma unroll
            for (int ks = 0; ks < 2; ++ks) {
                const int bo = row * 128 + ((ks * 64 + fq * 16) ^ ((row & 7) << 4));
                bfr[ni][ks] = *(const s16x8*)((const char*)sB + bo);
            }
        }
        #pragma unroll
        for (int ks = 0; ks < 2; ++ks)
            #pragma unroll
            for (int mi = 0; mi < 4; ++mi)
                #pragma unroll
                for (int ni = 0; ni < 4; ++ni)
                    acc[mi][ni] = __builtin_amdgcn_mfma_f32_16x16x32_bf16(
                        af[mi][ks], bfr[ni][ks], acc[mi][ni], 0, 0, 0);
        __syncthreads();
    }

    // epilogue: C/D layout col = lane&15, row = (lane>>4)*4 + reg
    #pragma unroll
    for (int mi = 0; mi < 4; ++mi) {
        #pragma unroll
        for (int j = 0; j < 4; ++j) {
            const int r = m0 + wm * 64 + mi * 16 + fq * 4 + j;
            #pragma unroll
            for (int ni = 0; ni < 4; ++ni) {
                const int c = n0 + wn * 64 + ni * 16 + fr;
                const float v = acc[mi][ni][j];
                if (c < n1)      C0[(size_t)r * ld0 + c]        = v;
                else if (c < n2) C1[(size_t)r * ld1 + (c - n1)] = v;
                else if (c < n3) C2[(size_t)r * ld2 + (c - n2)] = v;
            }
        }
    }
}

// ---------------------------------------------------------------------------
// Depthwise causal conv(4) + bias + SiLU. xBC layout: [NROWS][CONV_DIM].
// ---------------------------------------------------------------------------
__global__ __launch_bounds__(256) void conv_silu(const float* __restrict__ xBC,
                                                 const float* __restrict__ conv_w,
                                                 const float* __restrict__ conv_b,
                                                 float* __restrict__ xconv)
{
    int idx = blockIdx.x * 256 + threadIdx.x;
    if (idx >= NROWS * CONV_DIM) return;
    int c   = idx % CONV_DIM;
    int row = idx / CONV_DIM;      // b*SEQLEN + l
    int l   = row % SEQLEN;
    int b   = row / SEQLEN;
    float w0 = conv_w[c*4+0], w1 = conv_w[c*4+1], w2 = conv_w[c*4+2], w3 = conv_w[c*4+3];
    const float* src = xBC + (size_t)(b * SEQLEN) * CONV_DIM + c;
    float acc = conv_b[c];
    if (l >= 3) {
        acc += src[(size_t)(l-3)*CONV_DIM]*w0 + src[(size_t)(l-2)*CONV_DIM]*w1
             + src[(size_t)(l-1)*CONV_DIM]*w2 + src[(size_t)l*CONV_DIM]*w3;
    } else {
        if (l >= 2) acc += src[(size_t)(l-2)*CONV_DIM]*w1;
        if (l >= 1) acc += src[(size_t)(l-1)*CONV_DIM]*w2;
        acc += src[(size_t)l*CONV_DIM]*w3;
    }
    xconv[idx] = acc / (1.f + expf(-acc));   // SiLU
}

// ---------------------------------------------------------------------------
// dt = softplus(dtraw + dt_bias)
// ---------------------------------------------------------------------------
__global__ __launch_bounds__(256) void dt_softplus(const float* __restrict__ dtraw,
                                                   const float* __restrict__ dt_bias,
                                                   float* __restrict__ dtw)
{
    int idx = blockIdx.x * 256 + threadIdx.x;
    if (idx >= NROWS * NHEADS) return;
    int h = idx & (NHEADS - 1);
    float v = dtraw[idx] + dt_bias[h];
    dtw[idx] = (v > 20.f) ? v : log1pf(expf(v));
}

// ---------------------------------------------------------------------------
// Phase A: per-(b,h,chunk) local chunk state
// ---------------------------------------------------------------------------
__global__ __launch_bounds__(256) void chunk_state(
    const float* __restrict__ xconv, const float* __restrict__ dtw,
    const float* __restrict__ A_log, float* __restrict__ Sbuf,
    float* __restrict__ Tbuf)
{
    const int blk = blockIdx.x;
    const int k  = blk & (NCHUNK-1);
    const int bh = blk >> 5;
    const int b  = bh >> 4, h = bh & 15;
    const int tid = threadIdx.x;
    const float A = -expf(A_log[h]);

    __shared__ float sdt[CHUNK], sL[CHUNK], sW[CHUNK];
    __shared__ float sB[CHUNK][D_STATE];

    const int t0 = k * CHUNK;
    const float* xc = xconv + (size_t)(b*SEQLEN + t0) * CONV_DIM;

    if (tid < CHUNK)
        sdt[tid] = dtw[(size_t)(b*SEQLEN + t0 + tid)*NHEADS + h];
    for (int i = tid; i < CHUNK*D_STATE; i += 256) {
        int s = i >> 6, n = i & 63;
        sB[s][n] = xc[(size_t)s*CONV_DIM + D_INNER + n];
    }
    __syncthreads();
    if (tid < CHUNK) {
        float a = 0.f;
        for (int r = 0; r <= tid; ++r) a += sdt[r] * A;
        sL[tid] = a;
    }
    __syncthreads();
    const float T = sL[CHUNK-1];
    if (tid < CHUNK) sW[tid] = __expf(T - sL[tid]) * sdt[tid];
    __syncthreads();

    const int p = tid & 127, nh = tid >> 7;
    float acc[32];
    #pragma unroll
    for (int i = 0; i < 32; ++i) acc[i] = 0.f;
    for (int s = 0; s < CHUNK; ++s) {
        float xs = xc[(size_t)s*CONV_DIM + h*HEADDIM + p];
        float wx = sW[s] * xs;
        #pragma unroll
        for (int i4 = 0; i4 < 8; ++i4) {
            float4 b4 = *(const float4*)&sB[s][nh*32 + i4*4];
            acc[i4*4+0] += wx*b4.x; acc[i4*4+1] += wx*b4.y;
            acc[i4*4+2] += wx*b4.z; acc[i4*4+3] += wx*b4.w;
        }
    }
    float* So = Sbuf + ((size_t)bh*NCHUNK + k)*(D_STATE*HEADDIM);
    #pragma unroll
    for (int i = 0; i < 32; ++i)
        So[(size_t)(nh*32+i)*HEADDIM + p] = acc[i];
    if (tid == 0) Tbuf[bh*NCHUNK + k] = T;
}

// ---------------------------------------------------------------------------
// Inter-chunk sequential pass
// ---------------------------------------------------------------------------
__global__ __launch_bounds__(128) void chunk_seq(float* __restrict__ Sbuf,
                                                 const float* __restrict__ Tbuf)
{
    const int bh = blockIdx.x;
    const int p  = threadIdx.x;
    float* Sb = Sbuf + (size_t)bh*NCHUNK*(D_STATE*HEADDIM);
    const float* Tb = Tbuf + bh*NCHUNK;
    float run[D_STATE];
    #pragma unroll
    for (int n = 0; n < D_STATE; ++n) run[n] = 0.f;
    for (int k = 0; k < NCHUNK; ++k) {
        float eT = __expf(Tb[k]);
        float* Sk = Sb + (size_t)k*(D_STATE*HEADDIM);
        #pragma unroll
        for (int n = 0; n < D_STATE; ++n) {
            float tmp = Sk[(size_t)n*HEADDIM + p];
            Sk[(size_t)n*HEADDIM + p] = run[n];
            run[n] = run[n]*eT + tmp;
        }
    }
}

// ---------------------------------------------------------------------------
// Phase B: per-(b,h,chunk) outputs
// ---------------------------------------------------------------------------
__global__ __launch_bounds__(256) void chunk_output(
    const float* __restrict__ xconv, const float* __restrict__ dtw,
    const float* __restrict__ A_log, const float* __restrict__ D_param,
    const float* __restrict__ Sbuf, float* __restrict__ y)
{
    const int blk = blockIdx.x;
    const int k  = blk & (NCHUNK-1);
    const int bh = blk >> 5;
    const int b  = bh >> 4, h = bh & 15;
    const int tid = threadIdx.x;
    const float A  = -expf(A_log[h]);
    const float Dp = D_param[h];

    __shared__ float sdt[CHUNK], sL[CHUNK], sedA[CHUNK], seL[CHUNK];
    __shared__ float sB[CHUNK][D_STATE];
    __shared__ float sMt[CHUNK + D_STATE][CHUNK];

    const int t0 = k * CHUNK;
    const float* xc = xconv + (size_t)(b*SEQLEN + t0) * CONV_DIM;

    if (tid < CHUNK)
        sdt[tid] = dtw[(size_t)(b*SEQLEN + t0 + tid)*NHEADS + h];
    for (int i = tid; i < CHUNK*D_STATE; i += 256) {
        int s = i >> 6, n = i & 63;
        sB[s][n] = xc[(size_t)s*CONV_DIM + D_INNER + n];
    }
    __syncthreads();
    if (tid < CHUNK) {
        float a = 0.f;
        for (int r = 0; r <= tid; ++r) a += sdt[r] * A;
        sL[tid]   = a;
        sedA[tid] = __expf(sdt[tid] * A);
        seL[tid]  = __expf(a);
    }
    __syncthreads();

    {
        const int t    = tid & 63;
        const int sh   = tid >> 6;
        const int sbeg = sh * 16;
        float4 c4[16];
        const float4* Crow = (const float4*)(xc + (size_t)t*CONV_DIM + D_INNER + D_STATE);
        #pragma unroll
        for (int i = 0; i < 16; ++i) c4[i] = Crow[i];

        const int shi = (t < sbeg + 15) ? t : (sbeg + 15);
        if (shi >= sbeg) {
            float e = __expf(sL[t] - sL[shi]);
            for (int s = shi; s >= sbeg; --s) {
                float dot = 0.f;
                #pragma unroll
                for (int i = 0; i < 16; ++i) {
                    float4 b4 = *(const float4*)&sB[s][i*4];
                    dot += c4[i].x*b4.x + c4[i].y*b4.y
                         + c4[i].z*b4.z + c4[i].w*b4.w;
                }
                sMt[s][t] = e * sdt[s] * dot;
                e *= sedA[s];
            }
        }
        for (int s = (shi >= sbeg ? shi+1 : sbeg); s < sbeg + 16; ++s)
            sMt[s][t] = 0.f;
        const float* CrowS = xc + (size_t)t*CONV_DIM + D_INNER + D_STATE;
        const float el = seL[t];
        #pragma unroll
        for (int j = 0; j < 16; ++j) {
            int n = sbeg + j;
            sMt[CHUNK + n][t] = el * CrowS[n];
        }
    }
    __syncthreads();

    {
        const int p  = tid & 127;
        const int th = tid >> 7;
        const float* Sinit = Sbuf + ((size_t)bh*NCHUNK + k)*(D_STATE*HEADDIM);
        float acc[32];
        #pragma unroll
        for (int i = 0; i < 32; ++i) acc[i] = 0.f;

        const int smax = th ? CHUNK : 32;
        for (int s = 0; s < smax; ++s) {
            float xs = xc[(size_t)s*CONV_DIM + h*HEADDIM + p];
            #pragma unroll
            for (int i4 = 0; i4 < 8; ++i4) {
                float4 m4 = *(const float4*)&sMt[s][th*32 + i4*4];
                acc[i4*4+0] += m4.x*xs; acc[i4*4+1] += m4.y*xs;
                acc[i4*4+2] += m4.z*xs; acc[i4*4+3] += m4.w*xs;
            }
        }
        for (int n = 0; n < D_STATE; ++n) {
            float xs = Sinit[(size_t)n*HEADDIM + p];
            #pragma unroll
            for (int i4 = 0; i4 < 8; ++i4) {
                float4 m4 = *(const float4*)&sMt[CHUNK + n][th*32 + i4*4];
                acc[i4*4+0] += m4.x*xs; acc[i4*4+1] += m4.y*xs;
                acc[i4*4+2] += m4.z*xs; acc[i4*4+3] += m4.w*xs;
            }
        }
        float* yrow = y + ((size_t)(b*SEQLEN + t0 + th*32))*D_INNER + h*HEADDIM + p;
        #pragma unroll
        for (int i = 0; i < 32; ++i) {
            int t = th*32 + i;
            float xt = xc[(size_t)t*CONV_DIM + h*HEADDIM + p];
            yrow[(size_t)i*D_INNER] = acc[i] + Dp*xt;
        }
    }
}

// ---------------------------------------------------------------------------
// yg = y * silu(z); RMSNorm over D_INNER; output bf16 (out_proj A-operand)
// ---------------------------------------------------------------------------
__global__ __launch_bounds__(256) void gate_rmsnorm(const float* __restrict__ z,
                                                    const float* __restrict__ y,
                                                    const float* __restrict__ norm_w,
                                                    u16* __restrict__ yn)
{
    const int row = blockIdx.x;
    const int tid = threadIdx.x;
    const float* zr = z + (size_t)row * D_INNER;
    const float* yr = y + (size_t)row * D_INNER;
    u16*         o  = yn + (size_t)row * D_INNER;

    float vals[8];
    float ss = 0.f;
    #pragma unroll
    for (int i = 0; i < 8; ++i) {
        int c = tid + i * 256;
        float zv = zr[c];
        float g  = yr[c] * (zv / (1.f + expf(-zv)));
        vals[i] = g;
        ss += g * g;
    }
    #pragma unroll
    for (int off = 32; off > 0; off >>= 1) ss += __shfl_down(ss, off);
    __shared__ float red[4];
    __shared__ float sscale;
    int wid = tid >> 6, lane = tid & 63;
    if (lane == 0) red[wid] = ss;
    __syncthreads();
    if (tid == 0)
        sscale = rsqrtf((red[0]+red[1]+red[2]+red[3]) / (float)D_INNER + 1e-5f);
    __syncthreads();
    float rms = sscale;
    #pragma unroll
    for (int i = 0; i < 8; ++i) {
        int c = tid + i * 256;
        o[c] = f2bf(vals[i] * rms * norm_w[c]);
    }
}

// ---------------------------------------------------------------------------
extern "C" void kernel_launch(void* const* d_in, const int* in_sizes, int n_in,
                              void* d_out, int out_size, void* d_ws, size_t ws_size,
                              hipStream_t stream)
{
    const float* u          = (const float*)d_in[0];
    const float* in_proj_w  = (const float*)d_in[1];
    const float* conv_w     = (const float*)d_in[2];
    const float* conv_b     = (const float*)d_in[3];
    const float* dt_bias    = (const float*)d_in[4];
    const float* A_log      = (const float*)d_in[5];
    const float* D_param    = (const float*)d_in[6];
    const float* norm_w     = (const float*)d_in[7];
    const float* out_proj_w = (const float*)d_in[8];
    float* out = (float*)d_out;

    float* ws    = (float*)d_ws;
    float* z     = ws;                                   // 8,388,608 f
    float* xBC   = z     + (size_t)NROWS * D_INNER;      // 8,912,896 f
    float* dtraw = xBC   + (size_t)NROWS * CONV_DIM;     // 65,536 f
    float* xconv = dtraw + (size_t)NROWS * NHEADS;       // 8,912,896 f
    float* dtw   = xconv + (size_t)NROWS * CONV_DIM;     // 65,536 f
    float* yb    = dtw   + (size_t)NROWS * NHEADS;       // 8,388,608 f
    float* Tbuf  = yb    + (size_t)NROWS * D_INNER;      // 1,024 f
    // aliased (lifetime-disjoint) regions:
    float* Sbuf   = xBC;            // scan states (xBC dead after conv)
    u16*  u_bf    = (u16*)xconv;    // dead before conv writes xconv
    u16*  w_in_bf = (u16*)yb;       // dead before chunk_output writes yb
    u16*  w_out_bf= (u16*)xBC;      // after Sbuf is dead
    u16*  yn_bf   = (u16*)xconv;    // after chunk_output read xconv

    // 0) f32 -> bf16 conversions for in_proj GEMM operands
    cvt_bf16_x8<<<(NROWS*D_MODEL/8 + 255)/256, 256, 0, stream>>>(u, u_bf, NROWS*D_MODEL/8);
    cvt_win_pad<<<(NPAD*128 + 255)/256, 256, 0, stream>>>(in_proj_w, w_in_bf);

    // 1) in_proj GEMM (bf16 MFMA, split outputs: z | xBC | dtraw)
    dim3 g1(NPAD/128, NROWS/128);
    gemm_bf16_mfma<<<g1, 256, 0, stream>>>(u_bf, w_in_bf, D_MODEL,
                                           z, D_INNER, D_INNER,
                                           xBC, D_INNER + CONV_DIM, CONV_DIM,
                                           dtraw, D_IN_PROJ, NHEADS);

    // 2) conv + SiLU
    int nconv = NROWS * CONV_DIM;
    conv_silu<<<(nconv + 255) / 256, 256, 0, stream>>>(xBC, conv_w, conv_b, xconv);

    // 3) dt softplus
    dt_softplus<<<(NROWS * NHEADS + 255) / 256, 256, 0, stream>>>(dtraw, dt_bias, dtw);

    // 4) chunked scan
    chunk_state<<<BATCH*NHEADS*NCHUNK, 256, 0, stream>>>(xconv, dtw, A_log, Sbuf, Tbuf);
    chunk_seq<<<BATCH*NHEADS, 128, 0, stream>>>(Sbuf, Tbuf);
    chunk_output<<<BATCH*NHEADS*NCHUNK, 256, 0, stream>>>(xconv, dtw, A_log, D_param,
                                                          Sbuf, yb);

    // 5) out_proj weight conversion (Sbuf dead now), gate + RMSNorm -> bf16
    cvt_bf16_x8<<<(D_MODEL*D_INNER/8 + 255)/256, 256, 0, stream>>>(out_proj_w, w_out_bf,
                                                                   D_MODEL*D_INNER/8);
    gate_rmsnorm<<<NROWS, 256, 0, stream>>>(z, yb, norm_w, yn_bf);

    // 6) out_proj GEMM (bf16 MFMA): out[4096,1024] = yn @ Wo^T
    dim3 g6(D_MODEL/128, NROWS/128);
    gemm_bf16_mfma<<<g6, 256, 0, stream>>>(yn_bf, w_out_bf, D_INNER,
                                           out, D_MODEL, D_MODEL,
                                           out, D_MODEL, D_MODEL,
                                           out, D_MODEL, D_MODEL);
}

// Round 4
// 285.769 us; speedup vs baseline: 10.4961x; 1.8560x over previous
//
#include <hip/hip_runtime.h>
#include <cstdint>
#include <cstddef>

#define D_MODEL   1024
#define D_STATE   64
#define D_CONV    4
#define HEADDIM   128
#define NHEADS    16
#define D_INNER   2048
#define CONV_DIM  2176          // D_INNER + 2*D_STATE
#define D_IN_PROJ 4240          // 2*D_INNER + 2*D_STATE + NHEADS
#define NPAD      4352          // D_IN_PROJ padded to multiple of 128
#define BATCH     2
#define SEQLEN    2048
#define NROWS     (BATCH*SEQLEN)   // 4096
#define CHUNK     64
#define NCHUNK    (SEQLEN/CHUNK)   // 32

using u16   = unsigned short;
using s16x8 = __attribute__((ext_vector_type(8))) short;   // 8 bf16 (4 VGPRs)
using f32x4 = __attribute__((ext_vector_type(4))) float;   // MFMA accumulator

// ---------------------------------------------------------------------------
// helpers
// ---------------------------------------------------------------------------
__device__ __forceinline__ u16 f2bf(float f) {
    union { float f; unsigned u; } v; v.f = f;
    unsigned r = v.u + 0x7fffu + ((v.u >> 16) & 1u);   // round-to-nearest-even
    return (u16)(r >> 16);
}

__device__ __forceinline__ void gload16(const u16* g, u16* l) {
    __builtin_amdgcn_global_load_lds(
        (const __attribute__((address_space(1))) unsigned int*)g,
        (__attribute__((address_space(3))) unsigned int*)l, 16, 0, 0);
}

// ---------------------------------------------------------------------------
// f32 -> bf16 converters (vectorized, 8 elems/thread)
// ---------------------------------------------------------------------------
__global__ __launch_bounds__(256) void cvt_bf16_x8(const float* __restrict__ in,
                                                   u16* __restrict__ out, int n8)
{
    int i = blockIdx.x * 256 + threadIdx.x;
    if (i >= n8) return;
    const float4* p = (const float4*)(in + (size_t)i * 8);
    float4 a = p[0], b = p[1];
    u16 o[8] = {f2bf(a.x), f2bf(a.y), f2bf(a.z), f2bf(a.w),
                f2bf(b.x), f2bf(b.y), f2bf(b.z), f2bf(b.w)};
    *(uint4*)(out + (size_t)i * 8) = *(const uint4*)o;
}

// in_proj_w [4240][1024] -> bf16 [4352][1024], zero-padded rows
__global__ __launch_bounds__(256) void cvt_win_pad(const float* __restrict__ w,
                                                   u16* __restrict__ out)
{
    int i = blockIdx.x * 256 + threadIdx.x;     // 8 elems each
    if (i >= NPAD * 128) return;
    int row = i >> 7, seg = i & 127;
    u16 o[8] = {0, 0, 0, 0, 0, 0, 0, 0};
    if (row < D_IN_PROJ) {
        const float4* p = (const float4*)(w + (size_t)row * D_MODEL + seg * 8);
        float4 a = p[0], b = p[1];
        o[0]=f2bf(a.x); o[1]=f2bf(a.y); o[2]=f2bf(a.z); o[3]=f2bf(a.w);
        o[4]=f2bf(b.x); o[5]=f2bf(b.y); o[6]=f2bf(b.z); o[7]=f2bf(b.w);
    }
    *(uint4*)(out + (size_t)i * 8) = *(const uint4*)o;
}

// ---------------------------------------------------------------------------
// bf16 MFMA GEMM (NT): C[M,N] = A[M,K] @ B[N,K]^T, fp32 out.
// 128x128 tile, BK=64, 4 waves; T2 XOR-swizzle via pre-swizzled global src.
// ---------------------------------------------------------------------------
__global__ __launch_bounds__(256) void gemm_bf16_mfma(
    const u16* __restrict__ A, const u16* __restrict__ B, int K,
    float* __restrict__ C0, int n1, int ld0,
    float* __restrict__ C1, int n2, int ld1,
    float* __restrict__ C2, int n3, int ld2)
{
    __shared__ u16 sA[128 * 64];
    __shared__ u16 sB[128 * 64];
    const int tid  = threadIdx.x;
    const int wid  = tid >> 6;
    const int lane = tid & 63;
    const int wm   = wid >> 1, wn = wid & 1;
    const int m0   = blockIdx.y * 128, n0 = blockIdx.x * 128;

    const int lrow = lane >> 3;              // row within 8-row stripe
    const int lseg = (lane & 7) ^ lrow;      // XOR-swizzled 16B segment
    const u16* gA = A + (size_t)(m0 + lrow) * K + lseg * 8;
    const u16* gB = B + (size_t)(n0 + lrow) * K + lseg * 8;

    f32x4 acc[4][4];
    #pragma unroll
    for (int i = 0; i < 4; ++i)
        #pragma unroll
        for (int j = 0; j < 4; ++j)
            acc[i][j] = (f32x4){0.f, 0.f, 0.f, 0.f};

    const int fr = lane & 15, fq = lane >> 4;

    for (int k0 = 0; k0 < K; k0 += 64) {
        #pragma unroll
        for (int i = 0; i < 4; ++i) {
            const int r0 = (i * 4 + wid) * 8;
            gload16(gA + (size_t)r0 * K + k0, sA + r0 * 64);
            gload16(gB + (size_t)r0 * K + k0, sB + r0 * 64);
        }
        __syncthreads();

        s16x8 af[4][2], bfr[4][2];
        #pragma unroll
        for (int mi = 0; mi < 4; ++mi) {
            const int row = wm * 64 + mi * 16 + fr;
            #pragma unroll
            for (int ks = 0; ks < 2; ++ks) {
                const int bo = row * 128 + ((ks * 64 + fq * 16) ^ ((row & 7) << 4));
                af[mi][ks] = *(const s16x8*)((const char*)sA + bo);
            }
        }
        #pragma unroll
        for (int ni = 0; ni < 4; ++ni) {
            const int row = wn * 64 + ni * 16 + fr;
            #pragma unroll
            for (int ks = 0; ks < 2; ++ks) {
                const int bo = row * 128 + ((ks * 64 + fq * 16) ^ ((row & 7) << 4));
                bfr[ni][ks] = *(const s16x8*)((const char*)sB + bo);
            }
        }
        #pragma unroll
        for (int ks = 0; ks < 2; ++ks)
            #pragma unroll
            for (int mi = 0; mi < 4; ++mi)
                #pragma unroll
                for (int ni = 0; ni < 4; ++ni)
                    acc[mi][ni] = __builtin_amdgcn_mfma_f32_16x16x32_bf16(
                        af[mi][ks], bfr[ni][ks], acc[mi][ni], 0, 0, 0);
        __syncthreads();
    }

    #pragma unroll
    for (int mi = 0; mi < 4; ++mi) {
        #pragma unroll
        for (int j = 0; j < 4; ++j) {
            const int r = m0 + wm * 64 + mi * 16 + fq * 4 + j;
            #pragma unroll
            for (int ni = 0; ni < 4; ++ni) {
                const int c = n0 + wn * 64 + ni * 16 + fr;
                const float v = acc[mi][ni][j];
                if (c < n1)      C0[(size_t)r * ld0 + c]        = v;
                else if (c < n2) C1[(size_t)r * ld1 + (c - n1)] = v;
                else if (c < n3) C2[(size_t)r * ld2 + (c - n2)] = v;
            }
        }
    }
}

// ---------------------------------------------------------------------------
// Depthwise causal conv(4) + bias + SiLU. xBC layout: [NROWS][CONV_DIM].
// ---------------------------------------------------------------------------
__global__ __launch_bounds__(256) void conv_silu(const float* __restrict__ xBC,
                                                 const float* __restrict__ conv_w,
                                                 const float* __restrict__ conv_b,
                                                 float* __restrict__ xconv)
{
    int idx = blockIdx.x * 256 + threadIdx.x;
    if (idx >= NROWS * CONV_DIM) return;
    int c   = idx % CONV_DIM;
    int row = idx / CONV_DIM;      // b*SEQLEN + l
    int l   = row % SEQLEN;
    int b   = row / SEQLEN;
    float w0 = conv_w[c*4+0], w1 = conv_w[c*4+1], w2 = conv_w[c*4+2], w3 = conv_w[c*4+3];
    const float* src = xBC + (size_t)(b * SEQLEN) * CONV_DIM + c;
    float acc = conv_b[c];
    if (l >= 3) {
        acc += src[(size_t)(l-3)*CONV_DIM]*w0 + src[(size_t)(l-2)*CONV_DIM]*w1
             + src[(size_t)(l-1)*CONV_DIM]*w2 + src[(size_t)l*CONV_DIM]*w3;
    } else {
        if (l >= 2) acc += src[(size_t)(l-2)*CONV_DIM]*w1;
        if (l >= 1) acc += src[(size_t)(l-1)*CONV_DIM]*w2;
        acc += src[(size_t)l*CONV_DIM]*w3;
    }
    xconv[idx] = acc / (1.f + expf(-acc));   // SiLU
}

// ---------------------------------------------------------------------------
// dt = softplus(dtraw + dt_bias)
// ---------------------------------------------------------------------------
__global__ __launch_bounds__(256) void dt_softplus(const float* __restrict__ dtraw,
                                                   const float* __restrict__ dt_bias,
                                                   float* __restrict__ dtw)
{
    int idx = blockIdx.x * 256 + threadIdx.x;
    if (idx >= NROWS * NHEADS) return;
    int h = idx & (NHEADS - 1);
    float v = dtraw[idx] + dt_bias[h];
    dtw[idx] = (v > 20.f) ? v : log1pf(expf(v));
}

// ---------------------------------------------------------------------------
// Phase A: per-(b,h,chunk) local chunk state
// ---------------------------------------------------------------------------
__global__ __launch_bounds__(256) void chunk_state(
    const float* __restrict__ xconv, const float* __restrict__ dtw,
    const float* __restrict__ A_log, float* __restrict__ Sbuf,
    float* __restrict__ Tbuf)
{
    const int blk = blockIdx.x;
    const int k  = blk & (NCHUNK-1);
    const int bh = blk >> 5;
    const int b  = bh >> 4, h = bh & 15;
    const int tid = threadIdx.x;
    const float A = -expf(A_log[h]);

    __shared__ float sdt[CHUNK], sL[CHUNK], sW[CHUNK];
    __shared__ float sB[CHUNK][D_STATE];

    const int t0 = k * CHUNK;
    const float* xc = xconv + (size_t)(b*SEQLEN + t0) * CONV_DIM;

    if (tid < CHUNK)
        sdt[tid] = dtw[(size_t)(b*SEQLEN + t0 + tid)*NHEADS + h];
    for (int i = tid; i < CHUNK*D_STATE; i += 256) {
        int s = i >> 6, n = i & 63;
        sB[s][n] = xc[(size_t)s*CONV_DIM + D_INNER + n];
    }
    __syncthreads();
    if (tid < CHUNK) {
        float a = 0.f;
        for (int r = 0; r <= tid; ++r) a += sdt[r] * A;
        sL[tid] = a;
    }
    __syncthreads();
    const float T = sL[CHUNK-1];
    if (tid < CHUNK) sW[tid] = __expf(T - sL[tid]) * sdt[tid];
    __syncthreads();

    const int p = tid & 127, nh = tid >> 7;
    float acc[32];
    #pragma unroll
    for (int i = 0; i < 32; ++i) acc[i] = 0.f;
    for (int s = 0; s < CHUNK; ++s) {
        float xs = xc[(size_t)s*CONV_DIM + h*HEADDIM + p];
        float wx = sW[s] * xs;
        #pragma unroll
        for (int i4 = 0; i4 < 8; ++i4) {
            float4 b4 = *(const float4*)&sB[s][nh*32 + i4*4];
            acc[i4*4+0] += wx*b4.x; acc[i4*4+1] += wx*b4.y;
            acc[i4*4+2] += wx*b4.z; acc[i4*4+3] += wx*b4.w;
        }
    }
    float* So = Sbuf + ((size_t)bh*NCHUNK + k)*(D_STATE*HEADDIM);
    #pragma unroll
    for (int i = 0; i < 32; ++i)
        So[(size_t)(nh*32+i)*HEADDIM + p] = acc[i];
    if (tid == 0) Tbuf[bh*NCHUNK + k] = T;
}

// ---------------------------------------------------------------------------
// Inter-chunk sequential pass — PARALLEL over (n,p): 262144 independent
// chains of length NCHUNK.  8 blocks per bh, float4 per thread.
//   tmp = S[k]; S[k] = run; run = run*exp(T_k) + tmp
// ---------------------------------------------------------------------------
__global__ __launch_bounds__(256) void chunk_seq_par(float* __restrict__ Sbuf,
                                                     const float* __restrict__ Tbuf)
{
    const int blk = blockIdx.x;           // 32 bh * 8 = 256 blocks
    const int bh  = blk >> 3;
    const int sub = blk & 7;
    __shared__ float seT[NCHUNK];
    if (threadIdx.x < NCHUNK)
        seT[threadIdx.x] = __expf(Tbuf[bh*NCHUNK + threadIdx.x]);
    __syncthreads();

    const int idx4 = sub * 256 + threadIdx.x;    // float4 index in [0,2048)
    float4* base = (float4*)(Sbuf + (size_t)bh*NCHUNK*(D_STATE*HEADDIM)) + idx4;
    float4 run = {0.f, 0.f, 0.f, 0.f};
    for (int k = 0; k < NCHUNK; ++k) {
        float4* p = base + (size_t)k * (D_STATE*HEADDIM/4);
        float4 tmp = *p;
        *p = run;
        const float eT = seT[k];
        run.x = run.x*eT + tmp.x;
        run.y = run.y*eT + tmp.y;
        run.z = run.z*eT + tmp.z;
        run.w = run.w*eT + tmp.w;
    }
}

// ---------------------------------------------------------------------------
// Phase B: per-(b,h,chunk) outputs
// ---------------------------------------------------------------------------
__global__ __launch_bounds__(256) void chunk_output(
    const float* __restrict__ xconv, const float* __restrict__ dtw,
    const float* __restrict__ A_log, const float* __restrict__ D_param,
    const float* __restrict__ Sbuf, float* __restrict__ y)
{
    const int blk = blockIdx.x;
    const int k  = blk & (NCHUNK-1);
    const int bh = blk >> 5;
    const int b  = bh >> 4, h = bh & 15;
    const int tid = threadIdx.x;
    const float A  = -expf(A_log[h]);
    const float Dp = D_param[h];

    __shared__ float sdt[CHUNK], sL[CHUNK], sedA[CHUNK], seL[CHUNK];
    __shared__ float sB[CHUNK][D_STATE];
    __shared__ float sMt[CHUNK + D_STATE][CHUNK];

    const int t0 = k * CHUNK;
    const float* xc = xconv + (size_t)(b*SEQLEN + t0) * CONV_DIM;

    if (tid < CHUNK)
        sdt[tid] = dtw[(size_t)(b*SEQLEN + t0 + tid)*NHEADS + h];
    for (int i = tid; i < CHUNK*D_STATE; i += 256) {
        int s = i >> 6, n = i & 63;
        sB[s][n] = xc[(size_t)s*CONV_DIM + D_INNER + n];
    }
    __syncthreads();
    if (tid < CHUNK) {
        float a = 0.f;
        for (int r = 0; r <= tid; ++r) a += sdt[r] * A;
        sL[tid]   = a;
        sedA[tid] = __expf(sdt[tid] * A);
        seL[tid]  = __expf(a);
    }
    __syncthreads();

    {
        const int t    = tid & 63;
        const int sh   = tid >> 6;
        const int sbeg = sh * 16;
        float4 c4[16];
        const float4* Crow = (const float4*)(xc + (size_t)t*CONV_DIM + D_INNER + D_STATE);
        #pragma unroll
        for (int i = 0; i < 16; ++i) c4[i] = Crow[i];

        const int shi = (t < sbeg + 15) ? t : (sbeg + 15);
        if (shi >= sbeg) {
            float e = __expf(sL[t] - sL[shi]);
            for (int s = shi; s >= sbeg; --s) {
                float dot = 0.f;
                #pragma unroll
                for (int i = 0; i < 16; ++i) {
                    float4 b4 = *(const float4*)&sB[s][i*4];
                    dot += c4[i].x*b4.x + c4[i].y*b4.y
                         + c4[i].z*b4.z + c4[i].w*b4.w;
                }
                sMt[s][t] = e * sdt[s] * dot;
                e *= sedA[s];
            }
        }
        for (int s = (shi >= sbeg ? shi+1 : sbeg); s < sbeg + 16; ++s)
            sMt[s][t] = 0.f;
        const float* CrowS = xc + (size_t)t*CONV_DIM + D_INNER + D_STATE;
        const float el = seL[t];
        #pragma unroll
        for (int j = 0; j < 16; ++j) {
            int n = sbeg + j;
            sMt[CHUNK + n][t] = el * CrowS[n];
        }
    }
    __syncthreads();

    {
        const int p  = tid & 127;
        const int th = tid >> 7;
        const float* Sinit = Sbuf + ((size_t)bh*NCHUNK + k)*(D_STATE*HEADDIM);
        float acc[32];
        #pragma unroll
        for (int i = 0; i < 32; ++i) acc[i] = 0.f;

        const int smax = th ? CHUNK : 32;
        for (int s = 0; s < smax; ++s) {
            float xs = xc[(size_t)s*CONV_DIM + h*HEADDIM + p];
            #pragma unroll
            for (int i4 = 0; i4 < 8; ++i4) {
                float4 m4 = *(const float4*)&sMt[s][th*32 + i4*4];
                acc[i4*4+0] += m4.x*xs; acc[i4*4+1] += m4.y*xs;
                acc[i4*4+2] += m4.z*xs; acc[i4*4+3] += m4.w*xs;
            }
        }
        for (int n = 0; n < D_STATE; ++n) {
            float xs = Sinit[(size_t)n*HEADDIM + p];
            #pragma unroll
            for (int i4 = 0; i4 < 8; ++i4) {
                float4 m4 = *(const float4*)&sMt[CHUNK + n][th*32 + i4*4];
                acc[i4*4+0] += m4.x*xs; acc[i4*4+1] += m4.y*xs;
                acc[i4*4+2] += m4.z*xs; acc[i4*4+3] += m4.w*xs;
            }
        }
        float* yrow = y + ((size_t)(b*SEQLEN + t0 + th*32))*D_INNER + h*HEADDIM + p;
        #pragma unroll
        for (int i = 0; i < 32; ++i) {
            int t = th*32 + i;
            float xt = xc[(size_t)t*CONV_DIM + h*HEADDIM + p];
            yrow[(size_t)i*D_INNER] = acc[i] + Dp*xt;
        }
    }
}

// ---------------------------------------------------------------------------
// yg = y * silu(z); RMSNorm over D_INNER; output bf16 (out_proj A-operand)
// ---------------------------------------------------------------------------
__global__ __launch_bounds__(256) void gate_rmsnorm(const float* __restrict__ z,
                                                    const float* __restrict__ y,
                                                    const float* __restrict__ norm_w,
                                                    u16* __restrict__ yn)
{
    const int row = blockIdx.x;
    const int tid = threadIdx.x;
    const float* zr = z + (size_t)row * D_INNER;
    const float* yr = y + (size_t)row * D_INNER;
    u16*         o  = yn + (size_t)row * D_INNER;

    float vals[8];
    float ss = 0.f;
    #pragma unroll
    for (int i = 0; i < 8; ++i) {
        int c = tid + i * 256;
        float zv = zr[c];
        float g  = yr[c] * (zv / (1.f + expf(-zv)));
        vals[i] = g;
        ss += g * g;
    }
    #pragma unroll
    for (int off = 32; off > 0; off >>= 1) ss += __shfl_down(ss, off);
    __shared__ float red[4];
    __shared__ float sscale;
    int wid = tid >> 6, lane = tid & 63;
    if (lane == 0) red[wid] = ss;
    __syncthreads();
    if (tid == 0)
        sscale = rsqrtf((red[0]+red[1]+red[2]+red[3]) / (float)D_INNER + 1e-5f);
    __syncthreads();
    float rms = sscale;
    #pragma unroll
    for (int i = 0; i < 8; ++i) {
        int c = tid + i * 256;
        o[c] = f2bf(vals[i] * rms * norm_w[c]);
    }
}

// ---------------------------------------------------------------------------
extern "C" void kernel_launch(void* const* d_in, const int* in_sizes, int n_in,
                              void* d_out, int out_size, void* d_ws, size_t ws_size,
                              hipStream_t stream)
{
    const float* u          = (const float*)d_in[0];
    const float* in_proj_w  = (const float*)d_in[1];
    const float* conv_w     = (const float*)d_in[2];
    const float* conv_b     = (const float*)d_in[3];
    const float* dt_bias    = (const float*)d_in[4];
    const float* A_log      = (const float*)d_in[5];
    const float* D_param    = (const float*)d_in[6];
    const float* norm_w     = (const float*)d_in[7];
    const float* out_proj_w = (const float*)d_in[8];
    float* out = (float*)d_out;

    float* ws    = (float*)d_ws;
    float* z     = ws;                                   // 8,388,608 f
    float* xBC   = z     + (size_t)NROWS * D_INNER;      // 8,912,896 f
    float* dtraw = xBC   + (size_t)NROWS * CONV_DIM;     // 65,536 f
    float* xconv = dtraw + (size_t)NROWS * NHEADS;       // 8,912,896 f
    float* dtw   = xconv + (size_t)NROWS * CONV_DIM;     // 65,536 f
    float* yb    = dtw   + (size_t)NROWS * NHEADS;       // 8,388,608 f
    float* Tbuf  = yb    + (size_t)NROWS * D_INNER;      // 1,024 f
    // aliased (lifetime-disjoint) regions:
    float* Sbuf   = xBC;            // scan states (xBC dead after conv)
    u16*  u_bf    = (u16*)xconv;    // dead before conv writes xconv
    u16*  w_in_bf = (u16*)yb;       // dead before chunk_output writes yb
    u16*  w_out_bf= (u16*)xBC;      // after Sbuf is dead
    u16*  yn_bf   = (u16*)xconv;    // after chunk_output read xconv

    // 0) f32 -> bf16 conversions for in_proj GEMM operands
    cvt_bf16_x8<<<(NROWS*D_MODEL/8 + 255)/256, 256, 0, stream>>>(u, u_bf, NROWS*D_MODEL/8);
    cvt_win_pad<<<(NPAD*128 + 255)/256, 256, 0, stream>>>(in_proj_w, w_in_bf);

    // 1) in_proj GEMM (bf16 MFMA, split outputs: z | xBC | dtraw)
    dim3 g1(NPAD/128, NROWS/128);
    gemm_bf16_mfma<<<g1, 256, 0, stream>>>(u_bf, w_in_bf, D_MODEL,
                                           z, D_INNER, D_INNER,
                                           xBC, D_INNER + CONV_DIM, CONV_DIM,
                                           dtraw, D_IN_PROJ, NHEADS);

    // 2) conv + SiLU
    int nconv = NROWS * CONV_DIM;
    conv_silu<<<(nconv + 255) / 256, 256, 0, stream>>>(xBC, conv_w, conv_b, xconv);

    // 3) dt softplus
    dt_softplus<<<(NROWS * NHEADS + 255) / 256, 256, 0, stream>>>(dtraw, dt_bias, dtw);

    // 4) chunked scan
    chunk_state<<<BATCH*NHEADS*NCHUNK, 256, 0, stream>>>(xconv, dtw, A_log, Sbuf, Tbuf);
    chunk_seq_par<<<BATCH*NHEADS*8, 256, 0, stream>>>(Sbuf, Tbuf);
    chunk_output<<<BATCH*NHEADS*NCHUNK, 256, 0, stream>>>(xconv, dtw, A_log, D_param,
                                                          Sbuf, yb);

    // 5) out_proj weight conversion (Sbuf dead now), gate + RMSNorm -> bf16
    cvt_bf16_x8<<<(D_MODEL*D_INNER/8 + 255)/256, 256, 0, stream>>>(out_proj_w, w_out_bf,
                                                                   D_MODEL*D_INNER/8);
    gate_rmsnorm<<<NROWS, 256, 0, stream>>>(z, yb, norm_w, yn_bf);

    // 6) out_proj GEMM (bf16 MFMA): out[4096,1024] = yn @ Wo^T
    dim3 g6(D_MODEL/128, NROWS/128);
    gemm_bf16_mfma<<<g6, 256, 0, stream>>>(yn_bf, w_out_bf, D_INNER,
                                           out, D_MODEL, D_MODEL,
                                           out, D_MODEL, D_MODEL,
                                           out, D_MODEL, D_MODEL);
}

// Round 5
// 285.533 us; speedup vs baseline: 10.5048x; 1.0008x over previous
//
#include <hip/hip_runtime.h>
#include <cstdint>
#include <cstddef>

#define D_MODEL   1024
#define D_STATE   64
#define D_CONV    4
#define HEADDIM   128
#define NHEADS    16
#define D_INNER   2048
#define CONV_DIM  2176          // D_INNER + 2*D_STATE
#define D_IN_PROJ 4240          // 2*D_INNER + 2*D_STATE + NHEADS
#define NPAD      4352          // D_IN_PROJ padded to multiple of 128
#define BATCH     2
#define SEQLEN    2048
#define NROWS     (BATCH*SEQLEN)   // 4096
#define CHUNK     64
#define NCHUNK    (SEQLEN/CHUNK)   // 32

using u16   = unsigned short;
using s16x8 = __attribute__((ext_vector_type(8))) short;   // 8 bf16 (4 VGPRs)
using f32x4 = __attribute__((ext_vector_type(4))) float;   // MFMA accumulator

// ---------------------------------------------------------------------------
// helpers
// ---------------------------------------------------------------------------
__device__ __forceinline__ u16 f2bf(float f) {
    union { float f; unsigned u; } v; v.f = f;
    unsigned r = v.u + 0x7fffu + ((v.u >> 16) & 1u);   // round-to-nearest-even
    return (u16)(r >> 16);
}
__device__ __forceinline__ float bf2f(u16 x) {
    union { unsigned u; float f; } v; v.u = ((unsigned)x) << 16;
    return v.f;
}

__device__ __forceinline__ void gload16(const u16* g, u16* l) {
    __builtin_amdgcn_global_load_lds(
        (const __attribute__((address_space(1))) unsigned int*)g,
        (__attribute__((address_space(3))) unsigned int*)l, 16, 0, 0);
}

// ---------------------------------------------------------------------------
// f32 -> bf16 converters (vectorized, 8 elems/thread)
// ---------------------------------------------------------------------------
__global__ __launch_bounds__(256) void cvt_bf16_x8(const float* __restrict__ in,
                                                   u16* __restrict__ out, int n8)
{
    int i = blockIdx.x * 256 + threadIdx.x;
    if (i >= n8) return;
    const float4* p = (const float4*)(in + (size_t)i * 8);
    float4 a = p[0], b = p[1];
    u16 o[8] = {f2bf(a.x), f2bf(a.y), f2bf(a.z), f2bf(a.w),
                f2bf(b.x), f2bf(b.y), f2bf(b.z), f2bf(b.w)};
    *(uint4*)(out + (size_t)i * 8) = *(const uint4*)o;
}

// in_proj_w [4240][1024] -> bf16 [4352][1024], zero-padded rows
__global__ __launch_bounds__(256) void cvt_win_pad(const float* __restrict__ w,
                                                   u16* __restrict__ out)
{
    int i = blockIdx.x * 256 + threadIdx.x;     // 8 elems each
    if (i >= NPAD * 128) return;
    int row = i >> 7, seg = i & 127;
    u16 o[8] = {0, 0, 0, 0, 0, 0, 0, 0};
    if (row < D_IN_PROJ) {
        const float4* p = (const float4*)(w + (size_t)row * D_MODEL + seg * 8);
        float4 a = p[0], b = p[1];
        o[0]=f2bf(a.x); o[1]=f2bf(a.y); o[2]=f2bf(a.z); o[3]=f2bf(a.w);
        o[4]=f2bf(b.x); o[5]=f2bf(b.y); o[6]=f2bf(b.z); o[7]=f2bf(b.w);
    }
    *(uint4*)(out + (size_t)i * 8) = *(const uint4*)o;
}

// ---------------------------------------------------------------------------
// bf16 MFMA GEMM (NT): C[M,N] = A[M,K] @ B[N,K]^T, OutT in {u16, float}.
// 128x128 tile, BK=64, 4 waves; T2 XOR-swizzle via pre-swizzled global src;
// T3-minimum 2-phase LDS double-buffer (prefetch next tile before compute).
// ---------------------------------------------------------------------------
template<typename OutT>
__global__ __launch_bounds__(256) void gemm_bf16_mfma(
    const u16* __restrict__ A, const u16* __restrict__ B, int K,
    OutT* __restrict__ C0, int n1, int ld0,
    OutT* __restrict__ C1, int n2, int ld1,
    OutT* __restrict__ C2, int n3, int ld2)
{
    __shared__ u16 sA[2][128 * 64];
    __shared__ u16 sB[2][128 * 64];
    const int tid  = threadIdx.x;
    const int wid  = tid >> 6;
    const int lane = tid & 63;
    const int wm   = wid >> 1, wn = wid & 1;
    const int m0   = blockIdx.y * 128, n0 = blockIdx.x * 128;

    const int lrow = lane >> 3;              // row within 8-row stripe
    const int lseg = (lane & 7) ^ lrow;      // XOR-swizzled 16B segment
    const u16* gA = A + (size_t)(m0 + lrow) * K + lseg * 8;
    const u16* gB = B + (size_t)(n0 + lrow) * K + lseg * 8;

    f32x4 acc[4][4];
    #pragma unroll
    for (int i = 0; i < 4; ++i)
        #pragma unroll
        for (int j = 0; j < 4; ++j)
            acc[i][j] = (f32x4){0.f, 0.f, 0.f, 0.f};

    const int fr = lane & 15, fq = lane >> 4;
    const int nstep = K >> 6;

    auto stage = [&](int buf, int k0) {
        #pragma unroll
        for (int i = 0; i < 4; ++i) {
            const int r0 = (i * 4 + wid) * 8;
            gload16(gA + (size_t)r0 * K + k0, &sA[buf][r0 * 64]);
            gload16(gB + (size_t)r0 * K + k0, &sB[buf][r0 * 64]);
        }
    };

    stage(0, 0);
    int cur = 0;
    for (int step = 0; step < nstep; ++step) {
        __syncthreads();                 // vmcnt(0) drain: buf[cur] ready
        if (step + 1 < nstep)
            stage(cur ^ 1, (step + 1) * 64);   // prefetch overlaps compute

        s16x8 af[4][2], bfr[4][2];
        #pragma unroll
        for (int mi = 0; mi < 4; ++mi) {
            const int row = wm * 64 + mi * 16 + fr;
            #pragma unroll
            for (int ks = 0; ks < 2; ++ks) {
                const int bo = row * 128 + ((ks * 64 + fq * 16) ^ ((row & 7) << 4));
                af[mi][ks] = *(const s16x8*)((const char*)sA[cur] + bo);
            }
        }
        #pragma unroll
        for (int ni = 0; ni < 4; ++ni) {
            const int row = wn * 64 + ni * 16 + fr;
            #pragma unroll
            for (int ks = 0; ks < 2; ++ks) {
                const int bo = row * 128 + ((ks * 64 + fq * 16) ^ ((row & 7) << 4));
                bfr[ni][ks] = *(const s16x8*)((const char*)sB[cur] + bo);
            }
        }
        #pragma unroll
        for (int ks = 0; ks < 2; ++ks)
            #pragma unroll
            for (int mi = 0; mi < 4; ++mi)
                #pragma unroll
                for (int ni = 0; ni < 4; ++ni)
                    acc[mi][ni] = __builtin_amdgcn_mfma_f32_16x16x32_bf16(
                        af[mi][ks], bfr[ni][ks], acc[mi][ni], 0, 0, 0);
        cur ^= 1;
    }

    #pragma unroll
    for (int mi = 0; mi < 4; ++mi) {
        #pragma unroll
        for (int j = 0; j < 4; ++j) {
            const int r = m0 + wm * 64 + mi * 16 + fq * 4 + j;
            #pragma unroll
            for (int ni = 0; ni < 4; ++ni) {
                const int c = n0 + wn * 64 + ni * 16 + fr;
                const float v = acc[mi][ni][j];
                OutT ov;
                if constexpr (sizeof(OutT) == 2) ov = f2bf(v); else ov = v;
                if (c < n1)      C0[(size_t)r * ld0 + c]        = ov;
                else if (c < n2) C1[(size_t)r * ld1 + (c - n1)] = ov;
                else if (c < n3) C2[(size_t)r * ld2 + (c - n2)] = ov;
            }
        }
    }
}

// ---------------------------------------------------------------------------
// Depthwise causal conv(4) + bias + SiLU, bf16 in/out, 8 channels/thread.
// ---------------------------------------------------------------------------
__global__ __launch_bounds__(256) void conv_silu(const u16* __restrict__ xBC,
                                                 const float* __restrict__ conv_w,
                                                 const float* __restrict__ conv_b,
                                                 u16* __restrict__ xconv)
{
    int idx = blockIdx.x * 256 + threadIdx.x;          // one per 8 channels
    if (idx >= NROWS * (CONV_DIM / 8)) return;
    int c8  = idx % (CONV_DIM / 8);
    int row = idx / (CONV_DIM / 8);     // b*SEQLEN + l
    int l   = row % SEQLEN;
    int b   = row / SEQLEN;
    int c0  = c8 * 8;
    const u16* src = xBC + (size_t)(b * SEQLEN) * CONV_DIM + c0;

    uint4 z4 = {0u, 0u, 0u, 0u};
    uint4 v3 = *(const uint4*)(src + (size_t)l * CONV_DIM);
    uint4 v2 = (l >= 1) ? *(const uint4*)(src + (size_t)(l-1) * CONV_DIM) : z4;
    uint4 v1 = (l >= 2) ? *(const uint4*)(src + (size_t)(l-2) * CONV_DIM) : z4;
    uint4 v0 = (l >= 3) ? *(const uint4*)(src + (size_t)(l-3) * CONV_DIM) : z4;
    const u16* p0 = (const u16*)&v0; const u16* p1 = (const u16*)&v1;
    const u16* p2 = (const u16*)&v2; const u16* p3 = (const u16*)&v3;

    u16 o[8];
    #pragma unroll
    for (int j = 0; j < 8; ++j) {
        const float4 w4 = *(const float4*)(conv_w + (size_t)(c0 + j) * 4);
        float acc = conv_b[c0 + j]
                  + bf2f(p0[j]) * w4.x + bf2f(p1[j]) * w4.y
                  + bf2f(p2[j]) * w4.z + bf2f(p3[j]) * w4.w;
        o[j] = f2bf(acc / (1.f + expf(-acc)));   // SiLU
    }
    *(uint4*)(xconv + (size_t)row * CONV_DIM + c0) = *(const uint4*)o;
}

// ---------------------------------------------------------------------------
// dt = softplus(dtraw + dt_bias)
// ---------------------------------------------------------------------------
__global__ __launch_bounds__(256) void dt_softplus(const u16* __restrict__ dtraw,
                                                   const float* __restrict__ dt_bias,
                                                   float* __restrict__ dtw)
{
    int idx = blockIdx.x * 256 + threadIdx.x;
    if (idx >= NROWS * NHEADS) return;
    int h = idx & (NHEADS - 1);
    float v = bf2f(dtraw[idx]) + dt_bias[h];
    dtw[idx] = (v > 20.f) ? v : log1pf(expf(v));
}

// ---------------------------------------------------------------------------
// Phase A: per-(b,h,chunk) local chunk state
// ---------------------------------------------------------------------------
__global__ __launch_bounds__(256) void chunk_state(
    const u16* __restrict__ xconv, const float* __restrict__ dtw,
    const float* __restrict__ A_log, float* __restrict__ Sbuf,
    float* __restrict__ Tbuf)
{
    const int blk = blockIdx.x;
    const int k  = blk & (NCHUNK-1);
    const int bh = blk >> 5;
    const int b  = bh >> 4, h = bh & 15;
    const int tid = threadIdx.x;
    const float A = -expf(A_log[h]);

    __shared__ float sdt[CHUNK], sL[CHUNK], sW[CHUNK];
    __shared__ float sB[CHUNK][D_STATE];

    const int t0 = k * CHUNK;
    const u16* xc = xconv + (size_t)(b*SEQLEN + t0) * CONV_DIM;

    if (tid < CHUNK)
        sdt[tid] = dtw[(size_t)(b*SEQLEN + t0 + tid)*NHEADS + h];
    for (int i = tid; i < CHUNK*D_STATE; i += 256) {
        int s = i >> 6, n = i & 63;
        sB[s][n] = bf2f(xc[(size_t)s*CONV_DIM + D_INNER + n]);
    }
    __syncthreads();
    if (tid < CHUNK) {
        float a = 0.f;
        for (int r = 0; r <= tid; ++r) a += sdt[r] * A;
        sL[tid] = a;
    }
    __syncthreads();
    const float T = sL[CHUNK-1];
    if (tid < CHUNK) sW[tid] = __expf(T - sL[tid]) * sdt[tid];
    __syncthreads();

    const int p = tid & 127, nh = tid >> 7;
    float acc[32];
    #pragma unroll
    for (int i = 0; i < 32; ++i) acc[i] = 0.f;
    for (int s = 0; s < CHUNK; ++s) {
        float xs = bf2f(xc[(size_t)s*CONV_DIM + h*HEADDIM + p]);
        float wx = sW[s] * xs;
        #pragma unroll
        for (int i4 = 0; i4 < 8; ++i4) {
            float4 b4 = *(const float4*)&sB[s][nh*32 + i4*4];
            acc[i4*4+0] += wx*b4.x; acc[i4*4+1] += wx*b4.y;
            acc[i4*4+2] += wx*b4.z; acc[i4*4+3] += wx*b4.w;
        }
    }
    float* So = Sbuf + ((size_t)bh*NCHUNK + k)*(D_STATE*HEADDIM);
    #pragma unroll
    for (int i = 0; i < 32; ++i)
        So[(size_t)(nh*32+i)*HEADDIM + p] = acc[i];
    if (tid == 0) Tbuf[bh*NCHUNK + k] = T;
}

// ---------------------------------------------------------------------------
// Inter-chunk sequential pass — parallel over (n,p)
// ---------------------------------------------------------------------------
__global__ __launch_bounds__(256) void chunk_seq_par(float* __restrict__ Sbuf,
                                                     const float* __restrict__ Tbuf)
{
    const int blk = blockIdx.x;           // 32 bh * 8 = 256 blocks
    const int bh  = blk >> 3;
    const int sub = blk & 7;
    __shared__ float seT[NCHUNK];
    if (threadIdx.x < NCHUNK)
        seT[threadIdx.x] = __expf(Tbuf[bh*NCHUNK + threadIdx.x]);
    __syncthreads();

    const int idx4 = sub * 256 + threadIdx.x;    // float4 index in [0,2048)
    float4* base = (float4*)(Sbuf + (size_t)bh*NCHUNK*(D_STATE*HEADDIM)) + idx4;
    float4 run = {0.f, 0.f, 0.f, 0.f};
    for (int k = 0; k < NCHUNK; ++k) {
        float4* p = base + (size_t)k * (D_STATE*HEADDIM/4);
        float4 tmp = *p;
        *p = run;
        const float eT = seT[k];
        run.x = run.x*eT + tmp.x;
        run.y = run.y*eT + tmp.y;
        run.z = run.z*eT + tmp.z;
        run.w = run.w*eT + tmp.w;
    }
}

// ---------------------------------------------------------------------------
// Phase B: per-(b,h,chunk) outputs, bf16 in/out
// ---------------------------------------------------------------------------
__global__ __launch_bounds__(256) void chunk_output(
    const u16* __restrict__ xconv, const float* __restrict__ dtw,
    const float* __restrict__ A_log, const float* __restrict__ D_param,
    const float* __restrict__ Sbuf, u16* __restrict__ y)
{
    const int blk = blockIdx.x;
    const int k  = blk & (NCHUNK-1);
    const int bh = blk >> 5;
    const int b  = bh >> 4, h = bh & 15;
    const int tid = threadIdx.x;
    const float A  = -expf(A_log[h]);
    const float Dp = D_param[h];

    __shared__ float sdt[CHUNK], sL[CHUNK], sedA[CHUNK], seL[CHUNK];
    __shared__ float sB[CHUNK][D_STATE];
    __shared__ float sMt[CHUNK + D_STATE][CHUNK];

    const int t0 = k * CHUNK;
    const u16* xc = xconv + (size_t)(b*SEQLEN + t0) * CONV_DIM;

    if (tid < CHUNK)
        sdt[tid] = dtw[(size_t)(b*SEQLEN + t0 + tid)*NHEADS + h];
    for (int i = tid; i < CHUNK*D_STATE; i += 256) {
        int s = i >> 6, n = i & 63;
        sB[s][n] = bf2f(xc[(size_t)s*CONV_DIM + D_INNER + n]);
    }
    __syncthreads();
    if (tid < CHUNK) {
        float a = 0.f;
        for (int r = 0; r <= tid; ++r) a += sdt[r] * A;
        sL[tid]   = a;
        sedA[tid] = __expf(sdt[tid] * A);
        seL[tid]  = __expf(a);
    }
    __syncthreads();

    {
        const int t    = tid & 63;
        const int sh   = tid >> 6;
        const int sbeg = sh * 16;
        // load C row t (64 bf16) and convert
        float cfl[64];
        {
            const uint4* Crow = (const uint4*)(xc + (size_t)t*CONV_DIM + D_INNER + D_STATE);
            #pragma unroll
            for (int i = 0; i < 8; ++i) {
                uint4 v = Crow[i];
                const u16* pv = (const u16*)&v;
                #pragma unroll
                for (int j = 0; j < 8; ++j) cfl[i*8+j] = bf2f(pv[j]);
            }
        }

        const int shi = (t < sbeg + 15) ? t : (sbeg + 15);
        if (shi >= sbeg) {
            float e = __expf(sL[t] - sL[shi]);
            for (int s = shi; s >= sbeg; --s) {
                float dot = 0.f;
                #pragma unroll
                for (int i = 0; i < 16; ++i) {
                    float4 b4 = *(const float4*)&sB[s][i*4];
                    dot += cfl[i*4+0]*b4.x + cfl[i*4+1]*b4.y
                         + cfl[i*4+2]*b4.z + cfl[i*4+3]*b4.w;
                }
                sMt[s][t] = e * sdt[s] * dot;
                e *= sedA[s];
            }
        }
        for (int s = (shi >= sbeg ? shi+1 : sbeg); s < sbeg + 16; ++s)
            sMt[s][t] = 0.f;
        const float el = seL[t];
        #pragma unroll
        for (int j = 0; j < 16; ++j) {
            int n = sbeg + j;
            sMt[CHUNK + n][t] = el * cfl[n];
        }
    }
    __syncthreads();

    {
        const int p  = tid & 127;
        const int th = tid >> 7;
        const float* Sinit = Sbuf + ((size_t)bh*NCHUNK + k)*(D_STATE*HEADDIM);
        float acc[32];
        #pragma unroll
        for (int i = 0; i < 32; ++i) acc[i] = 0.f;

        const int smax = th ? CHUNK : 32;
        for (int s = 0; s < smax; ++s) {
            float xs = bf2f(xc[(size_t)s*CONV_DIM + h*HEADDIM + p]);
            #pragma unroll
            for (int i4 = 0; i4 < 8; ++i4) {
                float4 m4 = *(const float4*)&sMt[s][th*32 + i4*4];
                acc[i4*4+0] += m4.x*xs; acc[i4*4+1] += m4.y*xs;
                acc[i4*4+2] += m4.z*xs; acc[i4*4+3] += m4.w*xs;
            }
        }
        for (int n = 0; n < D_STATE; ++n) {
            float xs = Sinit[(size_t)n*HEADDIM + p];
            #pragma unroll
            for (int i4 = 0; i4 < 8; ++i4) {
                float4 m4 = *(const float4*)&sMt[CHUNK + n][th*32 + i4*4];
                acc[i4*4+0] += m4.x*xs; acc[i4*4+1] += m4.y*xs;
                acc[i4*4+2] += m4.z*xs; acc[i4*4+3] += m4.w*xs;
            }
        }
        u16* yrow = y + ((size_t)(b*SEQLEN + t0 + th*32))*D_INNER + h*HEADDIM + p;
        #pragma unroll
        for (int i = 0; i < 32; ++i) {
            int t = th*32 + i;
            float xt = bf2f(xc[(size_t)t*CONV_DIM + h*HEADDIM + p]);
            yrow[(size_t)i*D_INNER] = f2bf(acc[i] + Dp*xt);
        }
    }
}

// ---------------------------------------------------------------------------
// yg = y * silu(z); RMSNorm over D_INNER; bf16 in, bf16 out
// ---------------------------------------------------------------------------
__global__ __launch_bounds__(256) void gate_rmsnorm(const u16* __restrict__ z,
                                                    const u16* __restrict__ y,
                                                    const float* __restrict__ norm_w,
                                                    u16* __restrict__ yn)
{
    const int row = blockIdx.x;
    const int tid = threadIdx.x;
    const u16* zr = z + (size_t)row * D_INNER + tid * 8;
    const u16* yr = y + (size_t)row * D_INNER + tid * 8;
    u16*       o  = yn + (size_t)row * D_INNER + tid * 8;

    uint4 zv4 = *(const uint4*)zr;
    uint4 yv4 = *(const uint4*)yr;
    const u16* zp = (const u16*)&zv4;
    const u16* yp = (const u16*)&yv4;

    float vals[8];
    float ss = 0.f;
    #pragma unroll
    for (int j = 0; j < 8; ++j) {
        float zv = bf2f(zp[j]);
        float g  = bf2f(yp[j]) * (zv / (1.f + expf(-zv)));
        vals[j] = g;
        ss += g * g;
    }
    #pragma unroll
    for (int off = 32; off > 0; off >>= 1) ss += __shfl_down(ss, off);
    __shared__ float red[4];
    __shared__ float sscale;
    int wid = tid >> 6, lane = tid & 63;
    if (lane == 0) red[wid] = ss;
    __syncthreads();
    if (tid == 0)
        sscale = rsqrtf((red[0]+red[1]+red[2]+red[3]) / (float)D_INNER + 1e-5f);
    __syncthreads();
    float rms = sscale;
    const float4* nw = (const float4*)(norm_w + tid * 8);
    float4 w0 = nw[0], w1 = nw[1];
    float wv[8] = {w0.x,w0.y,w0.z,w0.w,w1.x,w1.y,w1.z,w1.w};
    u16 ov[8];
    #pragma unroll
    for (int j = 0; j < 8; ++j) ov[j] = f2bf(vals[j] * rms * wv[j]);
    *(uint4*)o = *(const uint4*)ov;
}

// ---------------------------------------------------------------------------
extern "C" void kernel_launch(void* const* d_in, const int* in_sizes, int n_in,
                              void* d_out, int out_size, void* d_ws, size_t ws_size,
                              hipStream_t stream)
{
    const float* u          = (const float*)d_in[0];
    const float* in_proj_w  = (const float*)d_in[1];
    const float* conv_w     = (const float*)d_in[2];
    const float* conv_b     = (const float*)d_in[3];
    const float* dt_bias    = (const float*)d_in[4];
    const float* A_log      = (const float*)d_in[5];
    const float* D_param    = (const float*)d_in[6];
    const float* norm_w     = (const float*)d_in[7];
    const float* out_proj_w = (const float*)d_in[8];
    float* out = (float*)d_out;

    char* w = (char*)d_ws;
    u16* z_bf     = (u16*)w;  w += (size_t)NROWS * D_INNER  * 2;   // 16.78 MB
    u16* xBC_bf   = (u16*)w;  w += (size_t)NROWS * CONV_DIM * 2;   // 17.83 MB
    u16* xconv_bf = (u16*)w;  w += (size_t)NROWS * CONV_DIM * 2;   // 17.83 MB
    u16* yb_bf    = (u16*)w;  w += (size_t)NROWS * D_INNER  * 2;   // 16.78 MB
    u16* dtraw_bf = (u16*)w;  w += (size_t)NROWS * NHEADS   * 2;   // 0.13 MB
    float* dtw    = (float*)w; w += (size_t)NROWS * NHEADS  * 4;   // 0.26 MB
    float* Tbuf   = (float*)w; w += (size_t)BATCH*NHEADS*NCHUNK * 4;
    float* Sbuf   = (float*)w; w += (size_t)BATCH*NHEADS*NCHUNK*D_STATE*HEADDIM * 4; // 33.55 MB
    u16* u_bf     = (u16*)w;  w += (size_t)NROWS * D_MODEL  * 2;   // 8.39 MB
    u16* w_in_bf  = (u16*)w;  w += (size_t)NPAD  * D_MODEL  * 2;   // 8.91 MB
    u16* w_out_bf = (u16*)w;  w += (size_t)D_MODEL * D_INNER * 2;  // 4.19 MB
    u16* yn_bf    = xconv_bf;   // xconv dead after chunk_output

    // 0) f32 -> bf16 conversions for in_proj GEMM operands
    cvt_bf16_x8<<<(NROWS*D_MODEL/8 + 255)/256, 256, 0, stream>>>(u, u_bf, NROWS*D_MODEL/8);
    cvt_win_pad<<<(NPAD*128 + 255)/256, 256, 0, stream>>>(in_proj_w, w_in_bf);

    // 1) in_proj GEMM (bf16 MFMA, bf16 split outputs: z | xBC | dtraw)
    dim3 g1(NPAD/128, NROWS/128);
    gemm_bf16_mfma<u16><<<g1, 256, 0, stream>>>(u_bf, w_in_bf, D_MODEL,
                                                z_bf, D_INNER, D_INNER,
                                                xBC_bf, D_INNER + CONV_DIM, CONV_DIM,
                                                dtraw_bf, D_IN_PROJ, NHEADS);

    // 2) conv + SiLU (bf16 -> bf16)
    int nconv8 = NROWS * (CONV_DIM/8);
    conv_silu<<<(nconv8 + 255) / 256, 256, 0, stream>>>(xBC_bf, conv_w, conv_b, xconv_bf);

    // 3) dt softplus
    dt_softplus<<<(NROWS * NHEADS + 255) / 256, 256, 0, stream>>>(dtraw_bf, dt_bias, dtw);

    // 4) chunked scan
    chunk_state<<<BATCH*NHEADS*NCHUNK, 256, 0, stream>>>(xconv_bf, dtw, A_log, Sbuf, Tbuf);
    chunk_seq_par<<<BATCH*NHEADS*8, 256, 0, stream>>>(Sbuf, Tbuf);
    chunk_output<<<BATCH*NHEADS*NCHUNK, 256, 0, stream>>>(xconv_bf, dtw, A_log, D_param,
                                                          Sbuf, yb_bf);

    // 5) out_proj weight conversion, gate + RMSNorm -> bf16
    cvt_bf16_x8<<<(D_MODEL*D_INNER/8 + 255)/256, 256, 0, stream>>>(out_proj_w, w_out_bf,
                                                                   D_MODEL*D_INNER/8);
    gate_rmsnorm<<<NROWS, 256, 0, stream>>>(z_bf, yb_bf, norm_w, yn_bf);

    // 6) out_proj GEMM (bf16 MFMA, f32 out)
    dim3 g6(D_MODEL/128, NROWS/128);
    gemm_bf16_mfma<float><<<g6, 256, 0, stream>>>(yn_bf, w_out_bf, D_INNER,
                                                  out, D_MODEL, D_MODEL,
                                                  out, D_MODEL, D_MODEL,
                                                  out, D_MODEL, D_MODEL);
}

// Round 6
// 247.468 us; speedup vs baseline: 12.1206x; 1.1538x over previous
//
#include <hip/hip_runtime.h>
#include <cstdint>
#include <cstddef>

#define D_MODEL   1024
#define D_STATE   64
#define D_CONV    4
#define HEADDIM   128
#define NHEADS    16
#define D_INNER   2048
#define CONV_DIM  2176          // D_INNER + 2*D_STATE
#define D_IN_PROJ 4240          // 2*D_INNER + 2*D_STATE + NHEADS
#define NPAD      4352          // D_IN_PROJ padded to multiple of 128
#define BATCH     2
#define SEQLEN    2048
#define NROWS     (BATCH*SEQLEN)   // 4096
#define CHUNK     64
#define NCHUNK    (SEQLEN/CHUNK)   // 32

using u16   = unsigned short;
using s16x8 = __attribute__((ext_vector_type(8))) short;   // 8 bf16 (4 VGPRs)
using f32x4 = __attribute__((ext_vector_type(4))) float;   // MFMA accumulator

// ---------------------------------------------------------------------------
// helpers
// ---------------------------------------------------------------------------
__device__ __forceinline__ u16 f2bf(float f) {
    union { float f; unsigned u; } v; v.f = f;
    unsigned r = v.u + 0x7fffu + ((v.u >> 16) & 1u);   // round-to-nearest-even
    return (u16)(r >> 16);
}
__device__ __forceinline__ float bf2f(u16 x) {
    union { unsigned u; float f; } v; v.u = ((unsigned)x) << 16;
    return v.f;
}

__device__ __forceinline__ void gload16(const u16* g, u16* l) {
    __builtin_amdgcn_global_load_lds(
        (const __attribute__((address_space(1))) unsigned int*)g,
        (__attribute__((address_space(3))) unsigned int*)l, 16, 0, 0);
}

// ---------------------------------------------------------------------------
// f32 -> bf16 converters (vectorized, 8 elems/thread)
// ---------------------------------------------------------------------------
__global__ __launch_bounds__(256) void cvt_bf16_x8(const float* __restrict__ in,
                                                   u16* __restrict__ out, int n8)
{
    int i = blockIdx.x * 256 + threadIdx.x;
    if (i >= n8) return;
    const float4* p = (const float4*)(in + (size_t)i * 8);
    float4 a = p[0], b = p[1];
    u16 o[8] = {f2bf(a.x), f2bf(a.y), f2bf(a.z), f2bf(a.w),
                f2bf(b.x), f2bf(b.y), f2bf(b.z), f2bf(b.w)};
    *(uint4*)(out + (size_t)i * 8) = *(const uint4*)o;
}

// in_proj_w [4240][1024] -> bf16 [4352][1024], zero-padded rows
__global__ __launch_bounds__(256) void cvt_win_pad(const float* __restrict__ w,
                                                   u16* __restrict__ out)
{
    int i = blockIdx.x * 256 + threadIdx.x;     // 8 elems each
    if (i >= NPAD * 128) return;
    int row = i >> 7, seg = i & 127;
    u16 o[8] = {0, 0, 0, 0, 0, 0, 0, 0};
    if (row < D_IN_PROJ) {
        const float4* p = (const float4*)(w + (size_t)row * D_MODEL + seg * 8);
        float4 a = p[0], b = p[1];
        o[0]=f2bf(a.x); o[1]=f2bf(a.y); o[2]=f2bf(a.z); o[3]=f2bf(a.w);
        o[4]=f2bf(b.x); o[5]=f2bf(b.y); o[6]=f2bf(b.z); o[7]=f2bf(b.w);
    }
    *(uint4*)(out + (size_t)i * 8) = *(const uint4*)o;
}

// ---------------------------------------------------------------------------
// bf16 MFMA GEMM (NT): C[M,N] = A[M,K] @ B[N,K]^T, OutT in {u16, float}.
// 128x128 tile, BK=64, 4 waves; T2 XOR-swizzle; 2-phase LDS double-buffer.
// ---------------------------------------------------------------------------
template<typename OutT>
__global__ __launch_bounds__(256) void gemm_bf16_mfma(
    const u16* __restrict__ A, const u16* __restrict__ B, int K,
    OutT* __restrict__ C0, int n1, int ld0,
    OutT* __restrict__ C1, int n2, int ld1,
    OutT* __restrict__ C2, int n3, int ld2)
{
    __shared__ u16 sA[2][128 * 64];
    __shared__ u16 sB[2][128 * 64];
    const int tid  = threadIdx.x;
    const int wid  = tid >> 6;
    const int lane = tid & 63;
    const int wm   = wid >> 1, wn = wid & 1;
    const int m0   = blockIdx.y * 128, n0 = blockIdx.x * 128;

    const int lrow = lane >> 3;              // row within 8-row stripe
    const int lseg = (lane & 7) ^ lrow;      // XOR-swizzled 16B segment
    const u16* gA = A + (size_t)(m0 + lrow) * K + lseg * 8;
    const u16* gB = B + (size_t)(n0 + lrow) * K + lseg * 8;

    f32x4 acc[4][4];
    #pragma unroll
    for (int i = 0; i < 4; ++i)
        #pragma unroll
        for (int j = 0; j < 4; ++j)
            acc[i][j] = (f32x4){0.f, 0.f, 0.f, 0.f};

    const int fr = lane & 15, fq = lane >> 4;
    const int nstep = K >> 6;

    auto stage = [&](int buf, int k0) {
        #pragma unroll
        for (int i = 0; i < 4; ++i) {
            const int r0 = (i * 4 + wid) * 8;
            gload16(gA + (size_t)r0 * K + k0, &sA[buf][r0 * 64]);
            gload16(gB + (size_t)r0 * K + k0, &sB[buf][r0 * 64]);
        }
    };

    stage(0, 0);
    int cur = 0;
    for (int step = 0; step < nstep; ++step) {
        __syncthreads();
        if (step + 1 < nstep)
            stage(cur ^ 1, (step + 1) * 64);

        s16x8 af[4][2], bfr[4][2];
        #pragma unroll
        for (int mi = 0; mi < 4; ++mi) {
            const int row = wm * 64 + mi * 16 + fr;
            #pragma unroll
            for (int ks = 0; ks < 2; ++ks) {
                const int bo = row * 128 + ((ks * 64 + fq * 16) ^ ((row & 7) << 4));
                af[mi][ks] = *(const s16x8*)((const char*)sA[cur] + bo);
            }
        }
        #pragma unroll
        for (int ni = 0; ni < 4; ++ni) {
            const int row = wn * 64 + ni * 16 + fr;
            #pragma unroll
            for (int ks = 0; ks < 2; ++ks) {
                const int bo = row * 128 + ((ks * 64 + fq * 16) ^ ((row & 7) << 4));
                bfr[ni][ks] = *(const s16x8*)((const char*)sB[cur] + bo);
            }
        }
        #pragma unroll
        for (int ks = 0; ks < 2; ++ks)
            #pragma unroll
            for (int mi = 0; mi < 4; ++mi)
                #pragma unroll
                for (int ni = 0; ni < 4; ++ni)
                    acc[mi][ni] = __builtin_amdgcn_mfma_f32_16x16x32_bf16(
                        af[mi][ks], bfr[ni][ks], acc[mi][ni], 0, 0, 0);
        cur ^= 1;
    }

    #pragma unroll
    for (int mi = 0; mi < 4; ++mi) {
        #pragma unroll
        for (int j = 0; j < 4; ++j) {
            const int r = m0 + wm * 64 + mi * 16 + fq * 4 + j;
            #pragma unroll
            for (int ni = 0; ni < 4; ++ni) {
                const int c = n0 + wn * 64 + ni * 16 + fr;
                const float v = acc[mi][ni][j];
                OutT ov;
                if constexpr (sizeof(OutT) == 2) ov = f2bf(v); else ov = v;
                if (c < n1)      C0[(size_t)r * ld0 + c]        = ov;
                else if (c < n2) C1[(size_t)r * ld1 + (c - n1)] = ov;
                else if (c < n3) C2[(size_t)r * ld2 + (c - n2)] = ov;
            }
        }
    }
}

// ---------------------------------------------------------------------------
// Depthwise causal conv(4) + bias + SiLU, bf16 in/out, 8 channels/thread.
// ---------------------------------------------------------------------------
__global__ __launch_bounds__(256) void conv_silu(const u16* __restrict__ xBC,
                                                 const float* __restrict__ conv_w,
                                                 const float* __restrict__ conv_b,
                                                 u16* __restrict__ xconv)
{
    int idx = blockIdx.x * 256 + threadIdx.x;          // one per 8 channels
    if (idx >= NROWS * (CONV_DIM / 8)) return;
    int c8  = idx % (CONV_DIM / 8);
    int row = idx / (CONV_DIM / 8);     // b*SEQLEN + l
    int l   = row % SEQLEN;
    int b   = row / SEQLEN;
    int c0  = c8 * 8;
    const u16* src = xBC + (size_t)(b * SEQLEN) * CONV_DIM + c0;

    uint4 z4 = {0u, 0u, 0u, 0u};
    uint4 v3 = *(const uint4*)(src + (size_t)l * CONV_DIM);
    uint4 v2 = (l >= 1) ? *(const uint4*)(src + (size_t)(l-1) * CONV_DIM) : z4;
    uint4 v1 = (l >= 2) ? *(const uint4*)(src + (size_t)(l-2) * CONV_DIM) : z4;
    uint4 v0 = (l >= 3) ? *(const uint4*)(src + (size_t)(l-3) * CONV_DIM) : z4;
    const u16* p0 = (const u16*)&v0; const u16* p1 = (const u16*)&v1;
    const u16* p2 = (const u16*)&v2; const u16* p3 = (const u16*)&v3;

    u16 o[8];
    #pragma unroll
    for (int j = 0; j < 8; ++j) {
        const float4 w4 = *(const float4*)(conv_w + (size_t)(c0 + j) * 4);
        float acc = conv_b[c0 + j]
                  + bf2f(p0[j]) * w4.x + bf2f(p1[j]) * w4.y
                  + bf2f(p2[j]) * w4.z + bf2f(p3[j]) * w4.w;
        o[j] = f2bf(acc / (1.f + expf(-acc)));   // SiLU
    }
    *(uint4*)(xconv + (size_t)row * CONV_DIM + c0) = *(const uint4*)o;
}

// ---------------------------------------------------------------------------
// dt = softplus(dtraw + dt_bias)
// ---------------------------------------------------------------------------
__global__ __launch_bounds__(256) void dt_softplus(const u16* __restrict__ dtraw,
                                                   const float* __restrict__ dt_bias,
                                                   float* __restrict__ dtw)
{
    int idx = blockIdx.x * 256 + threadIdx.x;
    if (idx >= NROWS * NHEADS) return;
    int h = idx & (NHEADS - 1);
    float v = bf2f(dtraw[idx]) + dt_bias[h];
    dtw[idx] = (v > 20.f) ? v : log1pf(expf(v));
}

// ---------------------------------------------------------------------------
// Phase A: chunk state.  S[n][p] = sum_s (W_s*B_s[n]) * x_s[p]  (bf16 out)
// Register-tiled 4n x 8p per thread; x staged in LDS via global_load_lds;
// W*B staged xor-swizzled.
// ---------------------------------------------------------------------------
__global__ __launch_bounds__(256) void chunk_state(
    const u16* __restrict__ xconv, const float* __restrict__ dtw,
    const float* __restrict__ A_log, u16* __restrict__ Sbuf,
    float* __restrict__ Tbuf)
{
    const int blk = blockIdx.x;
    const int k  = blk & (NCHUNK-1);
    const int bh = blk >> 5;
    const int b  = bh >> 4, h = bh & 15;
    const int tid = threadIdx.x;
    const int wid = tid >> 6, lane = tid & 63;
    const float A = -expf(A_log[h]);

    __shared__ float sdt[CHUNK], sW[CHUNK], sT;
    __shared__ float sWB[CHUNK * D_STATE];     // xor-swizzled rows (256B)
    __shared__ u16   sX[CHUNK * HEADDIM];      // linear (DMA-staged)

    const int t0 = k * CHUNK;
    const u16* xc = xconv + (size_t)(b*SEQLEN + t0) * CONV_DIM;

    if (tid < CHUNK)
        sdt[tid] = dtw[(size_t)(b*SEQLEN + t0 + tid)*NHEADS + h];
    __syncthreads();
    if (tid < CHUNK) {
        float a = 0.f, pref = 0.f;
        for (int r = 0; r < CHUNK; ++r) {
            a += sdt[r] * A;
            if (r == tid) pref = a;
        }
        sW[tid] = __expf(a - pref) * sdt[tid];   // exp(T - L_s) * dt_s
        if (tid == 0) sT = a;
    }
    __syncthreads();

    // stage x via DMA: 4 calls/wave, 4 rows per call
    #pragma unroll
    for (int c = 0; c < 4; ++c) {
        const int r = wid * 16 + c * 4 + (lane >> 4);
        const int seg = lane & 15;
        gload16(xc + (size_t)r * CONV_DIM + h * HEADDIM + seg * 8,
                sX + (wid * 16 + c * 4) * HEADDIM);
    }
    // stage W*B (f32, xor-swizzled rows)
    {
        const int s = tid >> 2, nb = tid & 3;
        const float wv = sW[s];
        uint4 b0 = *(const uint4*)(xc + (size_t)s*CONV_DIM + D_INNER + nb*16);
        uint4 b1 = *(const uint4*)(xc + (size_t)s*CONV_DIM + D_INNER + nb*16 + 8);
        const u16* pb0 = (const u16*)&b0; const u16* pb1 = (const u16*)&b1;
        float bv[16];
        #pragma unroll
        for (int j = 0; j < 8; ++j) { bv[j] = wv*bf2f(pb0[j]); bv[8+j] = wv*bf2f(pb1[j]); }
        #pragma unroll
        for (int u = 0; u < 4; ++u) {
            const int bo = s * 256 + ((nb * 64 + u * 16) ^ ((s & 7) << 4));
            *(float4*)((char*)sWB + bo) = *(const float4*)&bv[u*4];
        }
    }
    __syncthreads();

    // compute: thread (nn, pp) -> 4n x 8p
    const int nn = tid >> 4, pp = tid & 15;
    const int p0 = pp * 8, n0 = nn * 4;
    float acc[4][8];
    #pragma unroll
    for (int i = 0; i < 4; ++i)
        #pragma unroll
        for (int j = 0; j < 8; ++j) acc[i][j] = 0.f;

    for (int s = 0; s < CHUNK; ++s) {
        const int bo = s * 256 + ((nn * 16) ^ ((s & 7) << 4));
        float4 wb = *(const float4*)((const char*)sWB + bo);
        uint4 xv = *(const uint4*)&sX[s * HEADDIM + p0];
        const u16* xp = (const u16*)&xv;
        float xf[8];
        #pragma unroll
        for (int j = 0; j < 8; ++j) xf[j] = bf2f(xp[j]);
        #pragma unroll
        for (int j = 0; j < 8; ++j) {
            acc[0][j] += wb.x * xf[j];
            acc[1][j] += wb.y * xf[j];
            acc[2][j] += wb.z * xf[j];
            acc[3][j] += wb.w * xf[j];
        }
    }
    u16* So = Sbuf + ((size_t)bh*NCHUNK + k)*(D_STATE*HEADDIM);
    #pragma unroll
    for (int i = 0; i < 4; ++i) {
        u16 o[8];
        #pragma unroll
        for (int j = 0; j < 8; ++j) o[j] = f2bf(acc[i][j]);
        *(uint4*)(So + (size_t)(n0 + i) * HEADDIM + p0) = *(const uint4*)o;
    }
    if (tid == 0) Tbuf[bh*NCHUNK + k] = sT;
}

// ---------------------------------------------------------------------------
// Inter-chunk sequential pass (bf16 S, f32 accumulation), parallel over (n,p)
// ---------------------------------------------------------------------------
__global__ __launch_bounds__(256) void chunk_seq_par(u16* __restrict__ Sbuf,
                                                     const float* __restrict__ Tbuf)
{
    const int blk = blockIdx.x;           // 32 bh * 4 = 128 blocks
    const int bh  = blk >> 2;
    const int sub = blk & 3;
    __shared__ float seT[NCHUNK];
    if (threadIdx.x < NCHUNK)
        seT[threadIdx.x] = __expf(Tbuf[bh*NCHUNK + threadIdx.x]);
    __syncthreads();

    const int idx8 = sub * 256 + threadIdx.x;    // 8-elem index in [0,1024)
    u16* base = Sbuf + (size_t)bh*NCHUNK*(D_STATE*HEADDIM) + (size_t)idx8*8;
    float run[8];
    #pragma unroll
    for (int j = 0; j < 8; ++j) run[j] = 0.f;
    for (int k = 0; k < NCHUNK; ++k) {
        u16* p = base + (size_t)k * (D_STATE*HEADDIM);
        uint4 v = *(const uint4*)p;
        const u16* pv = (const u16*)&v;
        const float eT = seT[k];
        u16 o[8];
        #pragma unroll
        for (int j = 0; j < 8; ++j) {
            float tmp = bf2f(pv[j]);
            o[j] = f2bf(run[j]);
            run[j] = run[j] * eT + tmp;
        }
        *(uint4*)p = *(const uint4*)o;
    }
}

// ---------------------------------------------------------------------------
// Phase B: chunk outputs.
// Stage A: G = C @ B^T via MFMA (no transpose needed: both row-major over n),
//          decay epilogue -> sMt[s][t] (xor-swizzled f32); Mext rows 64+n =
//          exp(L_t)*C_t[n]; x staged in LDS bf16 via DMA.
// Stage B: register-tiled 4t x 8p per thread over 128 s' rows + D*x.
// ---------------------------------------------------------------------------
__global__ __launch_bounds__(256) void chunk_output(
    const u16* __restrict__ xconv, const float* __restrict__ dtw,
    const float* __restrict__ A_log, const float* __restrict__ D_param,
    const u16* __restrict__ Sbuf, u16* __restrict__ y)
{
    const int blk = blockIdx.x;
    const int k  = blk & (NCHUNK-1);
    const int bh = blk >> 5;
    const int b  = bh >> 4, h = bh & 15;
    const int tid = threadIdx.x;
    const int wid = tid >> 6, lane = tid & 63;
    const float A  = -expf(A_log[h]);
    const float Dp = D_param[h];

    __shared__ float sdt[CHUNK], sL[CHUNK], seL[CHUNK];
    __shared__ float sMt[(CHUNK + D_STATE) * CHUNK];  // [row s'|64+n][64 t], swz
    __shared__ u16   sX[CHUNK * HEADDIM];             // linear (DMA-staged)

    const int t0 = k * CHUNK;
    const u16* xc = xconv + (size_t)(b*SEQLEN + t0) * CONV_DIM;

    if (tid < CHUNK)
        sdt[tid] = dtw[(size_t)(b*SEQLEN + t0 + tid)*NHEADS + h];
    __syncthreads();
    if (tid < CHUNK) {
        float a = 0.f, pref = 0.f;
        for (int r = 0; r < CHUNK; ++r) {
            a += sdt[r] * A;
            if (r == tid) pref = a;
        }
        sL[tid]  = pref;
        seL[tid] = __expf(pref);
    }
    __syncthreads();

    // ---- stage x via DMA (overlaps with MFMA below) ----
    #pragma unroll
    for (int c = 0; c < 4; ++c) {
        const int r = wid * 16 + c * 4 + (lane >> 4);
        const int seg = lane & 15;
        gload16(xc + (size_t)r * CONV_DIM + h * HEADDIM + seg * 8,
                sX + (wid * 16 + c * 4) * HEADDIM);
    }

    // ---- G = C @ B^T via MFMA; wave w owns t-frag w ----
    {
        const int fr = lane & 15, fq = lane >> 4;
        const int t_row = wid * 16 + fr;
        s16x8 cfrag[2];
        #pragma unroll
        for (int ks = 0; ks < 2; ++ks)
            cfrag[ks] = *(const s16x8*)(xc + (size_t)t_row*CONV_DIM + D_INNER + D_STATE
                                        + ks*32 + fq*8);
        float4 sL4 = *(const float4*)&sL[wid * 16 + fq * 4];
        const float Lt[4] = {sL4.x, sL4.y, sL4.z, sL4.w};

        #pragma unroll
        for (int sf = 0; sf < 4; ++sf) {
            const int s_row = sf * 16 + fr;
            f32x4 g = (f32x4){0.f, 0.f, 0.f, 0.f};
            #pragma unroll
            for (int ks = 0; ks < 2; ++ks) {
                s16x8 bfrag = *(const s16x8*)(xc + (size_t)s_row*CONV_DIM + D_INNER
                                              + ks*32 + fq*8);
                g = __builtin_amdgcn_mfma_f32_16x16x32_bf16(cfrag[ks], bfrag, g, 0, 0, 0);
            }
            const float Ls  = sL[s_row];
            const float dts = sdt[s_row];
            float out[4];
            #pragma unroll
            for (int r = 0; r < 4; ++r) {
                const int t = wid * 16 + fq * 4 + r;
                const float e = __expf(fminf(Lt[r] - Ls, 0.f)) * dts;
                out[r] = (s_row <= t) ? g[r] * e : 0.f;
            }
            const int bo = s_row * 256 + ((wid * 64 + fq * 16) ^ ((s_row & 7) << 4));
            *(float4*)((char*)sMt + bo) = *(const float4*)out;
        }
    }

    // ---- Mext rows: sMt[64+n][t] = exp(L_t) * C_t[n] ----
    {
        const int t = tid >> 2, nb = tid & 3;
        const float el = seL[t];
        uint4 c0 = *(const uint4*)(xc + (size_t)t*CONV_DIM + D_INNER + D_STATE + nb*16);
        uint4 c1 = *(const uint4*)(xc + (size_t)t*CONV_DIM + D_INNER + D_STATE + nb*16 + 8);
        const u16* pc0 = (const u16*)&c0; const u16* pc1 = (const u16*)&c1;
        #pragma unroll
        for (int j = 0; j < 16; ++j) {
            const int n = nb * 16 + j;
            const float v = el * bf2f(j < 8 ? pc0[j] : pc1[j - 8]);
            const int bo = (CHUNK + n) * 256 + ((t * 4) ^ ((n & 7) << 4));
            *(float*)((char*)sMt + bo) = v;
        }
    }
    __syncthreads();

    // ---- Stage B: thread (tt, pp) -> 4t x 8p ----
    const int tt = tid >> 4, pp = tid & 15;
    const int p0 = pp * 8;
    const int ttoff = tt * 16;        // byte offset of t-col group
    float acc[4][8];
    #pragma unroll
    for (int i = 0; i < 4; ++i)
        #pragma unroll
        for (int j = 0; j < 8; ++j) acc[i][j] = 0.f;

    const int smax = tt * 4 + 4;      // causal: s <= t_max of this thread
    for (int s = 0; s < smax; ++s) {
        const int bo = s * 256 + (ttoff ^ ((s & 7) << 4));
        float4 m4 = *(const float4*)((const char*)sMt + bo);
        uint4 xv = *(const uint4*)&sX[s * HEADDIM + p0];
        const u16* xp = (const u16*)&xv;
        #pragma unroll
        for (int j = 0; j < 8; ++j) {
            const float xf = bf2f(xp[j]);
            acc[0][j] += m4.x * xf;
            acc[1][j] += m4.y * xf;
            acc[2][j] += m4.z * xf;
            acc[3][j] += m4.w * xf;
        }
    }
    const u16* Sinit = Sbuf + ((size_t)bh*NCHUNK + k)*(D_STATE*HEADDIM);
    for (int n = 0; n < D_STATE; ++n) {
        const int bo = (CHUNK + n) * 256 + (ttoff ^ ((n & 7) << 4));
        float4 m4 = *(const float4*)((const char*)sMt + bo);
        uint4 sv = *(const uint4*)(Sinit + (size_t)n * HEADDIM + p0);
        const u16* sp = (const u16*)&sv;
        #pragma unroll
        for (int j = 0; j < 8; ++j) {
            const float sf = bf2f(sp[j]);
            acc[0][j] += m4.x * sf;
            acc[1][j] += m4.y * sf;
            acc[2][j] += m4.z * sf;
            acc[3][j] += m4.w * sf;
        }
    }
    #pragma unroll
    for (int i = 0; i < 4; ++i) {
        const int t = tt * 4 + i;
        uint4 xv = *(const uint4*)&sX[t * HEADDIM + p0];
        const u16* xp = (const u16*)&xv;
        u16 o[8];
        #pragma unroll
        for (int j = 0; j < 8; ++j)
            o[j] = f2bf(acc[i][j] + Dp * bf2f(xp[j]));
        *(uint4*)(y + ((size_t)(b*SEQLEN + t0 + t))*D_INNER + h*HEADDIM + p0)
            = *(const uint4*)o;
    }
}

// ---------------------------------------------------------------------------
// yg = y * silu(z); RMSNorm over D_INNER; bf16 in, bf16 out
// ---------------------------------------------------------------------------
__global__ __launch_bounds__(256) void gate_rmsnorm(const u16* __restrict__ z,
                                                    const u16* __restrict__ y,
                                                    const float* __restrict__ norm_w,
                                                    u16* __restrict__ yn)
{
    const int row = blockIdx.x;
    const int tid = threadIdx.x;
    const u16* zr = z + (size_t)row * D_INNER + tid * 8;
    const u16* yr = y + (size_t)row * D_INNER + tid * 8;
    u16*       o  = yn + (size_t)row * D_INNER + tid * 8;

    uint4 zv4 = *(const uint4*)zr;
    uint4 yv4 = *(const uint4*)yr;
    const u16* zp = (const u16*)&zv4;
    const u16* yp = (const u16*)&yv4;

    float vals[8];
    float ss = 0.f;
    #pragma unroll
    for (int j = 0; j < 8; ++j) {
        float zv = bf2f(zp[j]);
        float g  = bf2f(yp[j]) * (zv / (1.f + expf(-zv)));
        vals[j] = g;
        ss += g * g;
    }
    #pragma unroll
    for (int off = 32; off > 0; off >>= 1) ss += __shfl_down(ss, off);
    __shared__ float red[4];
    __shared__ float sscale;
    int wid = tid >> 6, lane = tid & 63;
    if (lane == 0) red[wid] = ss;
    __syncthreads();
    if (tid == 0)
        sscale = rsqrtf((red[0]+red[1]+red[2]+red[3]) / (float)D_INNER + 1e-5f);
    __syncthreads();
    float rms = sscale;
    const float4* nw = (const float4*)(norm_w + tid * 8);
    float4 w0 = nw[0], w1 = nw[1];
    float wv[8] = {w0.x,w0.y,w0.z,w0.w,w1.x,w1.y,w1.z,w1.w};
    u16 ov[8];
    #pragma unroll
    for (int j = 0; j < 8; ++j) ov[j] = f2bf(vals[j] * rms * wv[j]);
    *(uint4*)o = *(const uint4*)ov;
}

// ---------------------------------------------------------------------------
extern "C" void kernel_launch(void* const* d_in, const int* in_sizes, int n_in,
                              void* d_out, int out_size, void* d_ws, size_t ws_size,
                              hipStream_t stream)
{
    const float* u          = (const float*)d_in[0];
    const float* in_proj_w  = (const float*)d_in[1];
    const float* conv_w     = (const float*)d_in[2];
    const float* conv_b     = (const float*)d_in[3];
    const float* dt_bias    = (const float*)d_in[4];
    const float* A_log      = (const float*)d_in[5];
    const float* D_param    = (const float*)d_in[6];
    const float* norm_w     = (const float*)d_in[7];
    const float* out_proj_w = (const float*)d_in[8];
    float* out = (float*)d_out;

    char* w = (char*)d_ws;
    u16* z_bf     = (u16*)w;  w += (size_t)NROWS * D_INNER  * 2;   // 16.78 MB
    u16* xBC_bf   = (u16*)w;  w += (size_t)NROWS * CONV_DIM * 2;   // 17.83 MB
    u16* xconv_bf = (u16*)w;  w += (size_t)NROWS * CONV_DIM * 2;   // 17.83 MB
    u16* yb_bf    = (u16*)w;  w += (size_t)NROWS * D_INNER  * 2;   // 16.78 MB
    u16* dtraw_bf = (u16*)w;  w += (size_t)NROWS * NHEADS   * 2;   // 0.13 MB
    float* dtw    = (float*)w; w += (size_t)NROWS * NHEADS  * 4;   // 0.26 MB
    float* Tbuf   = (float*)w; w += (size_t)BATCH*NHEADS*NCHUNK * 4;
    u16* Sbuf     = (u16*)w;  w += (size_t)BATCH*NHEADS*NCHUNK*D_STATE*HEADDIM * 2; // 16.78 MB
    u16* u_bf     = (u16*)w;  w += (size_t)NROWS * D_MODEL  * 2;   // 8.39 MB
    u16* w_in_bf  = (u16*)w;  w += (size_t)NPAD  * D_MODEL  * 2;   // 8.91 MB
    u16* w_out_bf = (u16*)w;  w += (size_t)D_MODEL * D_INNER * 2;  // 4.19 MB
    u16* yn_bf    = xconv_bf;   // xconv dead after chunk_output

    // 0) f32 -> bf16 conversions for in_proj GEMM operands
    cvt_bf16_x8<<<(NROWS*D_MODEL/8 + 255)/256, 256, 0, stream>>>(u, u_bf, NROWS*D_MODEL/8);
    cvt_win_pad<<<(NPAD*128 + 255)/256, 256, 0, stream>>>(in_proj_w, w_in_bf);

    // 1) in_proj GEMM (bf16 MFMA, bf16 split outputs: z | xBC | dtraw)
    dim3 g1(NPAD/128, NROWS/128);
    gemm_bf16_mfma<u16><<<g1, 256, 0, stream>>>(u_bf, w_in_bf, D_MODEL,
                                                z_bf, D_INNER, D_INNER,
                                                xBC_bf, D_INNER + CONV_DIM, CONV_DIM,
                                                dtraw_bf, D_IN_PROJ, NHEADS);

    // 2) conv + SiLU (bf16 -> bf16)
    int nconv8 = NROWS * (CONV_DIM/8);
    conv_silu<<<(nconv8 + 255) / 256, 256, 0, stream>>>(xBC_bf, conv_w, conv_b, xconv_bf);

    // 3) dt softplus
    dt_softplus<<<(NROWS * NHEADS + 255) / 256, 256, 0, stream>>>(dtraw_bf, dt_bias, dtw);

    // 4) chunked scan
    chunk_state<<<BATCH*NHEADS*NCHUNK, 256, 0, stream>>>(xconv_bf, dtw, A_log, Sbuf, Tbuf);
    chunk_seq_par<<<BATCH*NHEADS*4, 256, 0, stream>>>(Sbuf, Tbuf);
    chunk_output<<<BATCH*NHEADS*NCHUNK, 256, 0, stream>>>(xconv_bf, dtw, A_log, D_param,
                                                          Sbuf, yb_bf);

    // 5) out_proj weight conversion, gate + RMSNorm -> bf16
    cvt_bf16_x8<<<(D_MODEL*D_INNER/8 + 255)/256, 256, 0, stream>>>(out_proj_w, w_out_bf,
                                                                   D_MODEL*D_INNER/8);
    gate_rmsnorm<<<NROWS, 256, 0, stream>>>(z_bf, yb_bf, norm_w, yn_bf);

    // 6) out_proj GEMM (bf16 MFMA, f32 out)
    dim3 g6(D_MODEL/128, NROWS/128);
    gemm_bf16_mfma<float><<<g6, 256, 0, stream>>>(yn_bf, w_out_bf, D_INNER,
                                                  out, D_MODEL, D_MODEL,
                                                  out, D_MODEL, D_MODEL,
                                                  out, D_MODEL, D_MODEL);
}

// Round 7
// 243.019 us; speedup vs baseline: 12.3426x; 1.0183x over previous
//
#include <hip/hip_runtime.h>
#include <cstdint>
#include <cstddef>

#define D_MODEL   1024
#define D_STATE   64
#define D_CONV    4
#define HEADDIM   128
#define NHEADS    16
#define D_INNER   2048
#define CONV_DIM  2176          // D_INNER + 2*D_STATE
#define D_IN_PROJ 4240          // 2*D_INNER + 2*D_STATE + NHEADS
#define NPAD      4352          // D_IN_PROJ padded to multiple of 128
#define BATCH     2
#define SEQLEN    2048
#define NROWS     (BATCH*SEQLEN)   // 4096
#define CHUNK     64
#define NCHUNK    (SEQLEN/CHUNK)   // 32

using u16   = unsigned short;
using s16x8 = __attribute__((ext_vector_type(8))) short;   // 8 bf16 (4 VGPRs)
using f32x4 = __attribute__((ext_vector_type(4))) float;   // MFMA accumulator

// ---------------------------------------------------------------------------
// helpers
// ---------------------------------------------------------------------------
__device__ __forceinline__ u16 f2bf(float f) {
    union { float f; unsigned u; } v; v.f = f;
    unsigned r = v.u + 0x7fffu + ((v.u >> 16) & 1u);   // round-to-nearest-even
    return (u16)(r >> 16);
}
__device__ __forceinline__ float bf2f(u16 x) {
    union { unsigned u; float f; } v; v.u = ((unsigned)x) << 16;
    return v.f;
}

__device__ __forceinline__ void gload16(const u16* g, u16* l) {
    __builtin_amdgcn_global_load_lds(
        (const __attribute__((address_space(1))) unsigned int*)g,
        (__attribute__((address_space(3))) unsigned int*)l, 16, 0, 0);
}

__device__ __forceinline__ void cp8(const float* in, u16* out, int i) {
    const float4* p = (const float4*)(in + (size_t)i * 8);
    float4 a = p[0], b = p[1];
    u16 o[8] = {f2bf(a.x), f2bf(a.y), f2bf(a.z), f2bf(a.w),
                f2bf(b.x), f2bf(b.y), f2bf(b.z), f2bf(b.w)};
    *(uint4*)(out + (size_t)i * 8) = *(const uint4*)o;
}

// ---------------------------------------------------------------------------
// merged f32 -> bf16 conversion: u | in_proj_w (row-padded) | out_proj_w
// ---------------------------------------------------------------------------
#define CVT_N0 (NROWS*D_MODEL/8)      // 524288
#define CVT_N1 (NPAD*128)             // 557056
#define CVT_N2 (D_MODEL*D_INNER/8)    // 262144
__global__ __launch_bounds__(256) void cvt_all(
    const float* __restrict__ u, const float* __restrict__ w_in,
    const float* __restrict__ w_out,
    u16* __restrict__ u_bf, u16* __restrict__ w_in_bf, u16* __restrict__ w_out_bf)
{
    int i = blockIdx.x * 256 + threadIdx.x;
    if (i < CVT_N0) {
        cp8(u, u_bf, i);
    } else if (i < CVT_N0 + CVT_N1) {
        int j = i - CVT_N0;
        int row = j >> 7, seg = j & 127;
        u16 o[8] = {0,0,0,0,0,0,0,0};
        if (row < D_IN_PROJ) {
            const float4* p = (const float4*)(w_in + (size_t)row * D_MODEL + seg * 8);
            float4 a = p[0], b = p[1];
            o[0]=f2bf(a.x); o[1]=f2bf(a.y); o[2]=f2bf(a.z); o[3]=f2bf(a.w);
            o[4]=f2bf(b.x); o[5]=f2bf(b.y); o[6]=f2bf(b.z); o[7]=f2bf(b.w);
        }
        *(uint4*)(w_in_bf + (size_t)j * 8) = *(const uint4*)o;
    } else if (i < CVT_N0 + CVT_N1 + CVT_N2) {
        cp8(w_out, w_out_bf, i - CVT_N0 - CVT_N1);
    }
}

// ---------------------------------------------------------------------------
// bf16 MFMA GEMM (NT): C[M,N] = A[M,K] @ B[N,K]^T, OutT in {u16, float}.
// 128x128 tile, BK=64, 4 waves; T2 XOR-swizzle; T4 counted-vmcnt pipeline
// (never drain vmcnt(0) in main loop); T1 bijective XCD swizzle.
// Requires grid.x*grid.y % 8 == 0.
// ---------------------------------------------------------------------------
template<typename OutT>
__global__ __launch_bounds__(256) void gemm_bf16_mfma(
    const u16* __restrict__ A, const u16* __restrict__ B, int K,
    OutT* __restrict__ C0, int n1, int ld0,
    OutT* __restrict__ C1, int n2, int ld1,
    OutT* __restrict__ C2, int n3, int ld2)
{
    __shared__ u16 sA[2][128 * 64];
    __shared__ u16 sB[2][128 * 64];
    const int tid  = threadIdx.x;
    const int wid  = tid >> 6;
    const int lane = tid & 63;
    const int wm   = wid >> 1, wn = wid & 1;

    // T1: XCD-aware block swizzle (hw id -> logical tile)
    const int gx   = gridDim.x;
    const int nwg  = gx * gridDim.y;
    const int cpx  = nwg >> 3;
    int orig = blockIdx.y * gx + blockIdx.x;
    int wg   = (orig & 7) * cpx + (orig >> 3);
    const int m0 = (wg / gx) * 128, n0 = (wg % gx) * 128;

    const int lrow = lane >> 3;              // row within 8-row stripe
    const int lseg = (lane & 7) ^ lrow;      // XOR-swizzled 16B segment
    const u16* gA = A + (size_t)(m0 + lrow) * K + lseg * 8;
    const u16* gB = B + (size_t)(n0 + lrow) * K + lseg * 8;

    f32x4 acc[4][4];
    #pragma unroll
    for (int i = 0; i < 4; ++i)
        #pragma unroll
        for (int j = 0; j < 4; ++j)
            acc[i][j] = (f32x4){0.f, 0.f, 0.f, 0.f};

    const int fr = lane & 15, fq = lane >> 4;
    const int nstep = K >> 6;

    auto stage = [&](int buf, int k0) {
        #pragma unroll
        for (int i = 0; i < 4; ++i) {
            const int r0 = (i * 4 + wid) * 8;
            gload16(gA + (size_t)r0 * K + k0, &sA[buf][r0 * 64]);
            gload16(gB + (size_t)r0 * K + k0, &sB[buf][r0 * 64]);
        }
    };

    stage(0, 0);                               // 8 DMA loads in flight
    int cur = 0;
    for (int step = 0; step < nstep; ++step) {
        if (step + 1 < nstep) {
            stage(cur ^ 1, (step + 1) * 64);   // +8 in flight (tile t+1)
            asm volatile("s_waitcnt vmcnt(8)" ::: "memory");   // tile t landed
        } else {
            asm volatile("s_waitcnt vmcnt(0)" ::: "memory");   // final drain
        }
        __builtin_amdgcn_s_barrier();          // raw barrier: no vmcnt(0) drain
        __builtin_amdgcn_sched_barrier(0);

        s16x8 af[4][2], bfr[4][2];
        #pragma unroll
        for (int mi = 0; mi < 4; ++mi) {
            const int row = wm * 64 + mi * 16 + fr;
            #pragma unroll
            for (int ks = 0; ks < 2; ++ks) {
                const int bo = row * 128 + ((ks * 64 + fq * 16) ^ ((row & 7) << 4));
                af[mi][ks] = *(const s16x8*)((const char*)sA[cur] + bo);
            }
        }
        #pragma unroll
        for (int ni = 0; ni < 4; ++ni) {
            const int row = wn * 64 + ni * 16 + fr;
            #pragma unroll
            for (int ks = 0; ks < 2; ++ks) {
                const int bo = row * 128 + ((ks * 64 + fq * 16) ^ ((row & 7) << 4));
                bfr[ni][ks] = *(const s16x8*)((const char*)sB[cur] + bo);
            }
        }
        #pragma unroll
        for (int ks = 0; ks < 2; ++ks)
            #pragma unroll
            for (int mi = 0; mi < 4; ++mi)
                #pragma unroll
                for (int ni = 0; ni < 4; ++ni)
                    acc[mi][ni] = __builtin_amdgcn_mfma_f32_16x16x32_bf16(
                        af[mi][ks], bfr[ni][ks], acc[mi][ni], 0, 0, 0);

        __builtin_amdgcn_sched_barrier(0);
        __builtin_amdgcn_s_barrier();          // all reads of buf[cur] done
        cur ^= 1;
    }

    #pragma unroll
    for (int mi = 0; mi < 4; ++mi) {
        #pragma unroll
        for (int j = 0; j < 4; ++j) {
            const int r = m0 + wm * 64 + mi * 16 + fq * 4 + j;
            #pragma unroll
            for (int ni = 0; ni < 4; ++ni) {
                const int c = n0 + wn * 64 + ni * 16 + fr;
                const float v = acc[mi][ni][j];
                OutT ov;
                if constexpr (sizeof(OutT) == 2) ov = f2bf(v); else ov = v;
                if (c < n1)      C0[(size_t)r * ld0 + c]        = ov;
                else if (c < n2) C1[(size_t)r * ld1 + (c - n1)] = ov;
                else if (c < n3) C2[(size_t)r * ld2 + (c - n2)] = ov;
            }
        }
    }
}

// ---------------------------------------------------------------------------
// Depthwise causal conv(4) + bias + SiLU, bf16 in/out, 8 channels/thread.
// ---------------------------------------------------------------------------
__global__ __launch_bounds__(256) void conv_silu(const u16* __restrict__ xBC,
                                                 const float* __restrict__ conv_w,
                                                 const float* __restrict__ conv_b,
                                                 u16* __restrict__ xconv)
{
    int idx = blockIdx.x * 256 + threadIdx.x;          // one per 8 channels
    if (idx >= NROWS * (CONV_DIM / 8)) return;
    int c8  = idx % (CONV_DIM / 8);
    int row = idx / (CONV_DIM / 8);     // b*SEQLEN + l
    int l   = row % SEQLEN;
    int b   = row / SEQLEN;
    int c0  = c8 * 8;
    const u16* src = xBC + (size_t)(b * SEQLEN) * CONV_DIM + c0;

    uint4 z4 = {0u, 0u, 0u, 0u};
    uint4 v3 = *(const uint4*)(src + (size_t)l * CONV_DIM);
    uint4 v2 = (l >= 1) ? *(const uint4*)(src + (size_t)(l-1) * CONV_DIM) : z4;
    uint4 v1 = (l >= 2) ? *(const uint4*)(src + (size_t)(l-2) * CONV_DIM) : z4;
    uint4 v0 = (l >= 3) ? *(const uint4*)(src + (size_t)(l-3) * CONV_DIM) : z4;
    const u16* p0 = (const u16*)&v0; const u16* p1 = (const u16*)&v1;
    const u16* p2 = (const u16*)&v2; const u16* p3 = (const u16*)&v3;

    u16 o[8];
    #pragma unroll
    for (int j = 0; j < 8; ++j) {
        const float4 w4 = *(const float4*)(conv_w + (size_t)(c0 + j) * 4);
        float acc = conv_b[c0 + j]
                  + bf2f(p0[j]) * w4.x + bf2f(p1[j]) * w4.y
                  + bf2f(p2[j]) * w4.z + bf2f(p3[j]) * w4.w;
        o[j] = f2bf(acc / (1.f + expf(-acc)));   // SiLU
    }
    *(uint4*)(xconv + (size_t)row * CONV_DIM + c0) = *(const uint4*)o;
}

// ---------------------------------------------------------------------------
// dt = softplus(dtraw + dt_bias)
// ---------------------------------------------------------------------------
__global__ __launch_bounds__(256) void dt_softplus(const u16* __restrict__ dtraw,
                                                   const float* __restrict__ dt_bias,
                                                   float* __restrict__ dtw)
{
    int idx = blockIdx.x * 256 + threadIdx.x;
    if (idx >= NROWS * NHEADS) return;
    int h = idx & (NHEADS - 1);
    float v = bf2f(dtraw[idx]) + dt_bias[h];
    dtw[idx] = (v > 20.f) ? v : log1pf(expf(v));
}

// ---------------------------------------------------------------------------
// Phase A: chunk state.  S[n][p] = sum_s (W_s*B_s[n]) * x_s[p]  (bf16 out)
// ---------------------------------------------------------------------------
__global__ __launch_bounds__(256) void chunk_state(
    const u16* __restrict__ xconv, const float* __restrict__ dtw,
    const float* __restrict__ A_log, u16* __restrict__ Sbuf,
    float* __restrict__ Tbuf)
{
    const int blk = blockIdx.x;
    const int k  = blk & (NCHUNK-1);
    const int bh = blk >> 5;
    const int b  = bh >> 4, h = bh & 15;
    const int tid = threadIdx.x;
    const int wid = tid >> 6, lane = tid & 63;
    const float A = -expf(A_log[h]);

    __shared__ float sdt[CHUNK], sW[CHUNK], sT;
    __shared__ float sWB[CHUNK * D_STATE];     // xor-swizzled rows (256B)
    __shared__ u16   sX[CHUNK * HEADDIM];      // linear (DMA-staged)

    const int t0 = k * CHUNK;
    const u16* xc = xconv + (size_t)(b*SEQLEN + t0) * CONV_DIM;

    if (tid < CHUNK)
        sdt[tid] = dtw[(size_t)(b*SEQLEN + t0 + tid)*NHEADS + h];
    __syncthreads();
    if (tid < CHUNK) {
        float a = 0.f, pref = 0.f;
        for (int r = 0; r < CHUNK; ++r) {
            a += sdt[r] * A;
            if (r == tid) pref = a;
        }
        sW[tid] = __expf(a - pref) * sdt[tid];   // exp(T - L_s) * dt_s
        if (tid == 0) sT = a;
    }
    __syncthreads();

    // stage x via DMA: 4 calls/wave, 4 rows per call
    #pragma unroll
    for (int c = 0; c < 4; ++c) {
        const int r = wid * 16 + c * 4 + (lane >> 4);
        const int seg = lane & 15;
        gload16(xc + (size_t)r * CONV_DIM + h * HEADDIM + seg * 8,
                sX + (wid * 16 + c * 4) * HEADDIM);
    }
    // stage W*B (f32, xor-swizzled rows)
    {
        const int s = tid >> 2, nb = tid & 3;
        const float wv = sW[s];
        uint4 b0 = *(const uint4*)(xc + (size_t)s*CONV_DIM + D_INNER + nb*16);
        uint4 b1 = *(const uint4*)(xc + (size_t)s*CONV_DIM + D_INNER + nb*16 + 8);
        const u16* pb0 = (const u16*)&b0; const u16* pb1 = (const u16*)&b1;
        float bv[16];
        #pragma unroll
        for (int j = 0; j < 8; ++j) { bv[j] = wv*bf2f(pb0[j]); bv[8+j] = wv*bf2f(pb1[j]); }
        #pragma unroll
        for (int u = 0; u < 4; ++u) {
            const int bo = s * 256 + ((nb * 64 + u * 16) ^ ((s & 7) << 4));
            *(float4*)((char*)sWB + bo) = *(const float4*)&bv[u*4];
        }
    }
    __syncthreads();

    // compute: thread (nn, pp) -> 4n x 8p
    const int nn = tid >> 4, pp = tid & 15;
    const int p0 = pp * 8, n0 = nn * 4;
    float acc[4][8];
    #pragma unroll
    for (int i = 0; i < 4; ++i)
        #pragma unroll
        for (int j = 0; j < 8; ++j) acc[i][j] = 0.f;

    for (int s = 0; s < CHUNK; ++s) {
        const int bo = s * 256 + ((nn * 16) ^ ((s & 7) << 4));
        float4 wb = *(const float4*)((const char*)sWB + bo);
        uint4 xv = *(const uint4*)&sX[s * HEADDIM + p0];
        const u16* xp = (const u16*)&xv;
        float xf[8];
        #pragma unroll
        for (int j = 0; j < 8; ++j) xf[j] = bf2f(xp[j]);
        #pragma unroll
        for (int j = 0; j < 8; ++j) {
            acc[0][j] += wb.x * xf[j];
            acc[1][j] += wb.y * xf[j];
            acc[2][j] += wb.z * xf[j];
            acc[3][j] += wb.w * xf[j];
        }
    }
    u16* So = Sbuf + ((size_t)bh*NCHUNK + k)*(D_STATE*HEADDIM);
    #pragma unroll
    for (int i = 0; i < 4; ++i) {
        u16 o[8];
        #pragma unroll
        for (int j = 0; j < 8; ++j) o[j] = f2bf(acc[i][j]);
        *(uint4*)(So + (size_t)(n0 + i) * HEADDIM + p0) = *(const uint4*)o;
    }
    if (tid == 0) Tbuf[bh*NCHUNK + k] = sT;
}

// ---------------------------------------------------------------------------
// Inter-chunk sequential pass (bf16 S, f32 accumulation), parallel over (n,p)
// ---------------------------------------------------------------------------
__global__ __launch_bounds__(256) void chunk_seq_par(u16* __restrict__ Sbuf,
                                                     const float* __restrict__ Tbuf)
{
    const int blk = blockIdx.x;           // 32 bh * 4 = 128 blocks
    const int bh  = blk >> 2;
    const int sub = blk & 3;
    __shared__ float seT[NCHUNK];
    if (threadIdx.x < NCHUNK)
        seT[threadIdx.x] = __expf(Tbuf[bh*NCHUNK + threadIdx.x]);
    __syncthreads();

    const int idx8 = sub * 256 + threadIdx.x;    // 8-elem index in [0,1024)
    u16* base = Sbuf + (size_t)bh*NCHUNK*(D_STATE*HEADDIM) + (size_t)idx8*8;
    float run[8];
    #pragma unroll
    for (int j = 0; j < 8; ++j) run[j] = 0.f;
    for (int k = 0; k < NCHUNK; ++k) {
        u16* p = base + (size_t)k * (D_STATE*HEADDIM);
        uint4 v = *(const uint4*)p;
        const u16* pv = (const u16*)&v;
        const float eT = seT[k];
        u16 o[8];
        #pragma unroll
        for (int j = 0; j < 8; ++j) {
            float tmp = bf2f(pv[j]);
            o[j] = f2bf(run[j]);
            run[j] = run[j] * eT + tmp;
        }
        *(uint4*)p = *(const uint4*)o;
    }
}

// ---------------------------------------------------------------------------
// Phase B: chunk outputs (MFMA G = C@B^T, decay epilogue, reg-tiled stage B)
// ---------------------------------------------------------------------------
__global__ __launch_bounds__(256) void chunk_output(
    const u16* __restrict__ xconv, const float* __restrict__ dtw,
    const float* __restrict__ A_log, const float* __restrict__ D_param,
    const u16* __restrict__ Sbuf, u16* __restrict__ y)
{
    const int blk = blockIdx.x;
    const int k  = blk & (NCHUNK-1);
    const int bh = blk >> 5;
    const int b  = bh >> 4, h = bh & 15;
    const int tid = threadIdx.x;
    const int wid = tid >> 6, lane = tid & 63;
    const float A  = -expf(A_log[h]);
    const float Dp = D_param[h];

    __shared__ float sdt[CHUNK], sL[CHUNK], seL[CHUNK];
    __shared__ float sMt[(CHUNK + D_STATE) * CHUNK];  // [row s'|64+n][64 t], swz
    __shared__ u16   sX[CHUNK * HEADDIM];             // linear (DMA-staged)

    const int t0 = k * CHUNK;
    const u16* xc = xconv + (size_t)(b*SEQLEN + t0) * CONV_DIM;

    if (tid < CHUNK)
        sdt[tid] = dtw[(size_t)(b*SEQLEN + t0 + tid)*NHEADS + h];
    __syncthreads();
    if (tid < CHUNK) {
        float a = 0.f, pref = 0.f;
        for (int r = 0; r < CHUNK; ++r) {
            a += sdt[r] * A;
            if (r == tid) pref = a;
        }
        sL[tid]  = pref;
        seL[tid] = __expf(pref);
    }
    __syncthreads();

    // ---- stage x via DMA (overlaps with MFMA below) ----
    #pragma unroll
    for (int c = 0; c < 4; ++c) {
        const int r = wid * 16 + c * 4 + (lane >> 4);
        const int seg = lane & 15;
        gload16(xc + (size_t)r * CONV_DIM + h * HEADDIM + seg * 8,
                sX + (wid * 16 + c * 4) * HEADDIM);
    }

    // ---- G = C @ B^T via MFMA; wave w owns t-frag w ----
    {
        const int fr = lane & 15, fq = lane >> 4;
        const int t_row = wid * 16 + fr;
        s16x8 cfrag[2];
        #pragma unroll
        for (int ks = 0; ks < 2; ++ks)
            cfrag[ks] = *(const s16x8*)(xc + (size_t)t_row*CONV_DIM + D_INNER + D_STATE
                                        + ks*32 + fq*8);
        float4 sL4 = *(const float4*)&sL[wid * 16 + fq * 4];
        const float Lt[4] = {sL4.x, sL4.y, sL4.z, sL4.w};

        #pragma unroll
        for (int sf = 0; sf < 4; ++sf) {
            const int s_row = sf * 16 + fr;
            f32x4 g = (f32x4){0.f, 0.f, 0.f, 0.f};
            #pragma unroll
            for (int ks = 0; ks < 2; ++ks) {
                s16x8 bfrag = *(const s16x8*)(xc + (size_t)s_row*CONV_DIM + D_INNER
                                              + ks*32 + fq*8);
                g = __builtin_amdgcn_mfma_f32_16x16x32_bf16(cfrag[ks], bfrag, g, 0, 0, 0);
            }
            const float Ls  = sL[s_row];
            const float dts = sdt[s_row];
            float out[4];
            #pragma unroll
            for (int r = 0; r < 4; ++r) {
                const int t = wid * 16 + fq * 4 + r;
                const float e = __expf(fminf(Lt[r] - Ls, 0.f)) * dts;
                out[r] = (s_row <= t) ? g[r] * e : 0.f;
            }
            const int bo = s_row * 256 + ((wid * 64 + fq * 16) ^ ((s_row & 7) << 4));
            *(float4*)((char*)sMt + bo) = *(const float4*)out;
        }
    }

    // ---- Mext rows: sMt[64+n][t] = exp(L_t) * C_t[n] ----
    {
        const int t = tid >> 2, nb = tid & 3;
        const float el = seL[t];
        uint4 c0 = *(const uint4*)(xc + (size_t)t*CONV_DIM + D_INNER + D_STATE + nb*16);
        uint4 c1 = *(const uint4*)(xc + (size_t)t*CONV_DIM + D_INNER + D_STATE + nb*16 + 8);
        const u16* pc0 = (const u16*)&c0; const u16* pc1 = (const u16*)&c1;
        #pragma unroll
        for (int j = 0; j < 16; ++j) {
            const int n = nb * 16 + j;
            const float v = el * bf2f(j < 8 ? pc0[j] : pc1[j - 8]);
            const int bo = (CHUNK + n) * 256 + ((t * 4) ^ ((n & 7) << 4));
            *(float*)((char*)sMt + bo) = v;
        }
    }
    __syncthreads();

    // ---- Stage B: thread (tt, pp) -> 4t x 8p ----
    const int tt = tid >> 4, pp = tid & 15;
    const int p0 = pp * 8;
    const int ttoff = tt * 16;        // byte offset of t-col group
    float acc[4][8];
    #pragma unroll
    for (int i = 0; i < 4; ++i)
        #pragma unroll
        for (int j = 0; j < 8; ++j) acc[i][j] = 0.f;

    const int smax = tt * 4 + 4;      // causal: s <= t_max of this thread
    for (int s = 0; s < smax; ++s) {
        const int bo = s * 256 + (ttoff ^ ((s & 7) << 4));
        float4 m4 = *(const float4*)((const char*)sMt + bo);
        uint4 xv = *(const uint4*)&sX[s * HEADDIM + p0];
        const u16* xp = (const u16*)&xv;
        #pragma unroll
        for (int j = 0; j < 8; ++j) {
            const float xf = bf2f(xp[j]);
            acc[0][j] += m4.x * xf;
            acc[1][j] += m4.y * xf;
            acc[2][j] += m4.z * xf;
            acc[3][j] += m4.w * xf;
        }
    }
    const u16* Sinit = Sbuf + ((size_t)bh*NCHUNK + k)*(D_STATE*HEADDIM);
    for (int n = 0; n < D_STATE; ++n) {
        const int bo = (CHUNK + n) * 256 + (ttoff ^ ((n & 7) << 4));
        float4 m4 = *(const float4*)((const char*)sMt + bo);
        uint4 sv = *(const uint4*)(Sinit + (size_t)n * HEADDIM + p0);
        const u16* sp = (const u16*)&sv;
        #pragma unroll
        for (int j = 0; j < 8; ++j) {
            const float sf = bf2f(sp[j]);
            acc[0][j] += m4.x * sf;
            acc[1][j] += m4.y * sf;
            acc[2][j] += m4.z * sf;
            acc[3][j] += m4.w * sf;
        }
    }
    #pragma unroll
    for (int i = 0; i < 4; ++i) {
        const int t = tt * 4 + i;
        uint4 xv = *(const uint4*)&sX[t * HEADDIM + p0];
        const u16* xp = (const u16*)&xv;
        u16 o[8];
        #pragma unroll
        for (int j = 0; j < 8; ++j)
            o[j] = f2bf(acc[i][j] + Dp * bf2f(xp[j]));
        *(uint4*)(y + ((size_t)(b*SEQLEN + t0 + t))*D_INNER + h*HEADDIM + p0)
            = *(const uint4*)o;
    }
}

// ---------------------------------------------------------------------------
// yg = y * silu(z); RMSNorm over D_INNER; bf16 in, bf16 out
// ---------------------------------------------------------------------------
__global__ __launch_bounds__(256) void gate_rmsnorm(const u16* __restrict__ z,
                                                    const u16* __restrict__ y,
                                                    const float* __restrict__ norm_w,
                                                    u16* __restrict__ yn)
{
    const int row = blockIdx.x;
    const int tid = threadIdx.x;
    const u16* zr = z + (size_t)row * D_INNER + tid * 8;
    const u16* yr = y + (size_t)row * D_INNER + tid * 8;
    u16*       o  = yn + (size_t)row * D_INNER + tid * 8;

    uint4 zv4 = *(const uint4*)zr;
    uint4 yv4 = *(const uint4*)yr;
    const u16* zp = (const u16*)&zv4;
    const u16* yp = (const u16*)&yv4;

    float vals[8];
    float ss = 0.f;
    #pragma unroll
    for (int j = 0; j < 8; ++j) {
        float zv = bf2f(zp[j]);
        float g  = bf2f(yp[j]) * (zv / (1.f + expf(-zv)));
        vals[j] = g;
        ss += g * g;
    }
    #pragma unroll
    for (int off = 32; off > 0; off >>= 1) ss += __shfl_down(ss, off);
    __shared__ float red[4];
    __shared__ float sscale;
    int wid = tid >> 6, lane = tid & 63;
    if (lane == 0) red[wid] = ss;
    __syncthreads();
    if (tid == 0)
        sscale = rsqrtf((red[0]+red[1]+red[2]+red[3]) / (float)D_INNER + 1e-5f);
    __syncthreads();
    float rms = sscale;
    const float4* nw = (const float4*)(norm_w + tid * 8);
    float4 w0 = nw[0], w1 = nw[1];
    float wv[8] = {w0.x,w0.y,w0.z,w0.w,w1.x,w1.y,w1.z,w1.w};
    u16 ov[8];
    #pragma unroll
    for (int j = 0; j < 8; ++j) ov[j] = f2bf(vals[j] * rms * wv[j]);
    *(uint4*)o = *(const uint4*)ov;
}

// ---------------------------------------------------------------------------
extern "C" void kernel_launch(void* const* d_in, const int* in_sizes, int n_in,
                              void* d_out, int out_size, void* d_ws, size_t ws_size,
                              hipStream_t stream)
{
    const float* u          = (const float*)d_in[0];
    const float* in_proj_w  = (const float*)d_in[1];
    const float* conv_w     = (const float*)d_in[2];
    const float* conv_b     = (const float*)d_in[3];
    const float* dt_bias    = (const float*)d_in[4];
    const float* A_log      = (const float*)d_in[5];
    const float* D_param    = (const float*)d_in[6];
    const float* norm_w     = (const float*)d_in[7];
    const float* out_proj_w = (const float*)d_in[8];
    float* out = (float*)d_out;

    char* w = (char*)d_ws;
    u16* z_bf     = (u16*)w;  w += (size_t)NROWS * D_INNER  * 2;   // 16.78 MB
    u16* xBC_bf   = (u16*)w;  w += (size_t)NROWS * CONV_DIM * 2;   // 17.83 MB
    u16* xconv_bf = (u16*)w;  w += (size_t)NROWS * CONV_DIM * 2;   // 17.83 MB
    u16* yb_bf    = (u16*)w;  w += (size_t)NROWS * D_INNER  * 2;   // 16.78 MB
    u16* dtraw_bf = (u16*)w;  w += (size_t)NROWS * NHEADS   * 2;   // 0.13 MB
    float* dtw    = (float*)w; w += (size_t)NROWS * NHEADS  * 4;   // 0.26 MB
    float* Tbuf   = (float*)w; w += (size_t)BATCH*NHEADS*NCHUNK * 4;
    u16* Sbuf     = (u16*)w;  w += (size_t)BATCH*NHEADS*NCHUNK*D_STATE*HEADDIM * 2; // 16.78 MB
    u16* u_bf     = (u16*)w;  w += (size_t)NROWS * D_MODEL  * 2;   // 8.39 MB
    u16* w_in_bf  = (u16*)w;  w += (size_t)NPAD  * D_MODEL  * 2;   // 8.91 MB
    u16* w_out_bf = (u16*)w;  w += (size_t)D_MODEL * D_INNER * 2;  // 4.19 MB
    u16* yn_bf    = xconv_bf;   // xconv dead after chunk_output

    // 0) all f32 -> bf16 conversions in one dispatch
    cvt_all<<<(CVT_N0+CVT_N1+CVT_N2 + 255)/256, 256, 0, stream>>>(
        u, in_proj_w, out_proj_w, u_bf, w_in_bf, w_out_bf);

    // 1) in_proj GEMM (bf16 MFMA, bf16 split outputs: z | xBC | dtraw)
    dim3 g1(NPAD/128, NROWS/128);       // 34 x 32 = 1088 blocks (%8==0)
    gemm_bf16_mfma<u16><<<g1, 256, 0, stream>>>(u_bf, w_in_bf, D_MODEL,
                                                z_bf, D_INNER, D_INNER,
                                                xBC_bf, D_INNER + CONV_DIM, CONV_DIM,
                                                dtraw_bf, D_IN_PROJ, NHEADS);

    // 2) conv + SiLU (bf16 -> bf16)
    int nconv8 = NROWS * (CONV_DIM/8);
    conv_silu<<<(nconv8 + 255) / 256, 256, 0, stream>>>(xBC_bf, conv_w, conv_b, xconv_bf);

    // 3) dt softplus
    dt_softplus<<<(NROWS * NHEADS + 255) / 256, 256, 0, stream>>>(dtraw_bf, dt_bias, dtw);

    // 4) chunked scan
    chunk_state<<<BATCH*NHEADS*NCHUNK, 256, 0, stream>>>(xconv_bf, dtw, A_log, Sbuf, Tbuf);
    chunk_seq_par<<<BATCH*NHEADS*4, 256, 0, stream>>>(Sbuf, Tbuf);
    chunk_output<<<BATCH*NHEADS*NCHUNK, 256, 0, stream>>>(xconv_bf, dtw, A_log, D_param,
                                                          Sbuf, yb_bf);

    // 5) gate + RMSNorm -> bf16
    gate_rmsnorm<<<NROWS, 256, 0, stream>>>(z_bf, yb_bf, norm_w, yn_bf);

    // 6) out_proj GEMM (bf16 MFMA, f32 out)
    dim3 g6(D_MODEL/128, NROWS/128);    // 8 x 32 = 256 blocks (%8==0)
    gemm_bf16_mfma<float><<<g6, 256, 0, stream>>>(yn_bf, w_out_bf, D_INNER,
                                                  out, D_MODEL, D_MODEL,
                                                  out, D_MODEL, D_MODEL,
                                                  out, D_MODEL, D_MODEL);
}